// Round 7
// baseline (367.167 us; speedup 1.0000x reference)
//
#include <hip/hip_runtime.h>
#include <stdint.h>

// ---------- types ----------
typedef __bf16 bf16x8 __attribute__((ext_vector_type(8)));
typedef float f32x4 __attribute__((ext_vector_type(4)));
typedef short s16x8 __attribute__((ext_vector_type(8)));
typedef unsigned int u32x2 __attribute__((ext_vector_type(2)));

__device__ __forceinline__ unsigned short f2bf(float f) {
  unsigned u = __builtin_bit_cast(unsigned, f);
  u += 0x7fff + ((u >> 16) & 1);   // RNE
  return (unsigned short)(u >> 16);
}
__device__ __forceinline__ float bf2f(unsigned short b) {
  unsigned u = ((unsigned)b) << 16;
  return __builtin_bit_cast(float, u);
}

__device__ __forceinline__ void gload_lds16(const void* g, void* l) {
  __builtin_amdgcn_global_load_lds(
      (const __attribute__((address_space(1))) unsigned int*)g,
      (__attribute__((address_space(3))) unsigned int*)l, 16, 0, 0);
}

__device__ __forceinline__ f32x4 mfma16x16x32(bf16x8 a, bf16x8 b, f32x4 c) {
  return __builtin_amdgcn_mfma_f32_16x16x32_bf16(a, b, c, 0, 0, 0);
}
__device__ __forceinline__ bf16x8 bc8(s16x8 v) { return __builtin_bit_cast(bf16x8, v); }

// ---------- fp32 -> bf16 convert ----------
__global__ void k_f32_to_bf16(const float* __restrict__ in,
                              unsigned short* __restrict__ out, int n4) {
  int i = blockIdx.x * blockDim.x + threadIdx.x;
  if (i < n4) {
    float4 v = ((const float4*)in)[i];
    ushort4 o;
    o.x = f2bf(v.x); o.y = f2bf(v.y); o.z = f2bf(v.z); o.w = f2bf(v.w);
    ((ushort4*)out)[i] = o;
  }
}

// ---------- QKV GEMM with fused RoPE + hi/lo-split epilogue ----------
// Q is pre-scaled by 0.125 (exact in bf16) so flash skips the score scale.
__global__ __launch_bounds__(256) void k_gemm_qkv(
    const unsigned short* __restrict__ A, const unsigned short* __restrict__ Bm,
    unsigned short* __restrict__ Qh, unsigned short* __restrict__ Ql,
    unsigned short* __restrict__ Kh, unsigned short* __restrict__ Kl,
    unsigned short* __restrict__ Vb,
    const float* __restrict__ sin_t, const float* __restrict__ cos_t) {
  const int M_K = 1024;
  __shared__ unsigned short As[128 * 32];
  __shared__ unsigned short Bs[128 * 32];
  const int tid = threadIdx.x;
  const int lane = tid & 63;
  const int l15 = lane & 15, g = lane >> 4;
  const int wid = tid >> 6, wr = wid >> 1, wc = wid & 1;
  const long m0 = (long)blockIdx.y * 128, n0 = (long)blockIdx.x * 128;

  f32x4 acc[4][4] = {};

  for (int k0 = 0; k0 < M_K; k0 += 32) {
#pragma unroll
    for (int p = 0; p < 2; ++p) {
      int e = p * 256 + tid;
      int row = e >> 2, col = (e & 3) * 8;
      gload_lds16(A + (m0 + row) * M_K + k0 + col, (char*)As + e * 16);
      gload_lds16(Bm + (n0 + row) * M_K + k0 + col, (char*)Bs + e * 16);
    }
    __syncthreads();
    bf16x8 af[4], bfr[4];
#pragma unroll
    for (int i = 0; i < 4; ++i) {
      af[i]  = bc8(*(const s16x8*)&As[(wr * 64 + i * 16 + l15) * 32 + g * 8]);
      bfr[i] = bc8(*(const s16x8*)&Bs[(wc * 64 + i * 16 + l15) * 32 + g * 8]);
    }
#pragma unroll
    for (int mi = 0; mi < 4; ++mi)
#pragma unroll
      for (int ni = 0; ni < 4; ++ni)
        acc[mi][ni] = mfma16x16x32(af[mi], bfr[ni], acc[mi][ni]);
    __syncthreads();
  }

  const int colbase = (int)n0 + wc * 64;
  const int s  = colbase >> 10;           // 0=q 1=k 2=v
  const int h  = (colbase >> 6) & 15;
#pragma unroll
  for (int mi = 0; mi < 4; ++mi)
#pragma unroll
    for (int r = 0; r < 4; ++r) {
      long m = m0 + wr * 64 + mi * 16 + g * 4 + r;
      int b = (int)(m >> 11), n = (int)(m & 2047);
      long slab = ((long)(b * 16 + h)) * 131072 + (long)n * 64;
      float v0 = acc[mi][0][r], v1 = acc[mi][1][r];
      float v2 = acc[mi][2][r], v3 = acc[mi][3][r];
      if (s == 2) {
        Vb[slab + l15]      = f2bf(v0);
        Vb[slab + 16 + l15] = f2bf(v1);
        Vb[slab + 32 + l15] = f2bf(v2);
        Vb[slab + 48 + l15] = f2bf(v3);
      } else {
        float o0 = v0, o1 = v1, o2 = v2, o3 = v3;
        if (n >= 4) {
          const float* cs = cos_t + (long)(n - 4) * 64;
          const float* sn = sin_t + (long)(n - 4) * 64;
          float c0 = cs[l15], c1 = cs[16 + l15], c2 = cs[32 + l15], c3 = cs[48 + l15];
          float s0 = sn[l15], s1 = sn[16 + l15], s2 = sn[32 + l15], s3 = sn[48 + l15];
          float t0 = o0, t1 = o1;
          o0 = o0 * c0 - o2 * s0;  o1 = o1 * c1 - o3 * s1;
          o2 = o2 * c2 + t0 * s2;  o3 = o3 * c3 + t1 * s3;
        }
        if (s == 0) { o0 *= 0.125f; o1 *= 0.125f; o2 *= 0.125f; o3 *= 0.125f; }
        unsigned short* H = (s == 0) ? Qh : Kh;
        unsigned short* L = (s == 0) ? Ql : Kl;
        unsigned short h0 = f2bf(o0); H[slab + l15]      = h0; L[slab + l15]      = f2bf(o0 - bf2f(h0));
        unsigned short h1 = f2bf(o1); H[slab + 16 + l15] = h1; L[slab + 16 + l15] = f2bf(o1 - bf2f(h1));
        unsigned short h2 = f2bf(o2); H[slab + 32 + l15] = h2; L[slab + 32 + l15] = f2bf(o2 - bf2f(h2));
        unsigned short h3 = f2bf(o3); H[slab + 48 + l15] = h3; L[slab + 48 + l15] = f2bf(o3 - bf2f(h3));
      }
    }
}

// ---------- V transpose: Vb [bh][2048 n][64 d] -> Vt [bh][64 d][2048 n] ----------
// grid (8, 64), 256 thr.  LDS [64 d][256 key] u16 with unit-swizzle.
__global__ __launch_bounds__(256) void k_vtrans(const unsigned short* __restrict__ Vb,
                                                unsigned short* __restrict__ Vt) {
  __shared__ unsigned short T[64 * 256];
  const int tid = threadIdx.x;
  const int bh = blockIdx.y;
  const int n0 = blockIdx.x * 256;
  const long slab = (long)bh * 131072;
#pragma unroll
  for (int it = 0; it < 8; ++it) {
    int u = it * 256 + tid;            // 2048 units
    int key = u >> 3, dc = u & 7;
    s16x8 v = *(const s16x8*)&Vb[slab + (long)(n0 + key) * 64 + dc * 8];
#pragma unroll
    for (int i = 0; i < 8; ++i) {
      int d = dc * 8 + i;
      T[d * 256 + (key ^ (dc << 3))] = (unsigned short)v[i];
    }
  }
  __syncthreads();
#pragma unroll
  for (int it = 0; it < 8; ++it) {
    int w = it * 256 + tid;
    int d = w >> 5, nc = w & 31;
    int ncs = (nc & 24) | ((nc & 7) ^ (d >> 3));
    s16x8 v = *(const s16x8*)&T[d * 256 + ncs * 8];
    *(s16x8*)&Vt[slab + (long)d * 2048 + n0 + nc * 8] = v;
  }
}

// ---------- generic bf16 GEMM (final projection), f32 out + bias ----------
__global__ __launch_bounds__(256) void k_gemm_proj(
    const unsigned short* __restrict__ A, const unsigned short* __restrict__ Bm,
    float* __restrict__ Cf, const float* __restrict__ bias, int M, int N, int K) {
  __shared__ unsigned short As[128 * 32];
  __shared__ unsigned short Bs[128 * 32];
  const int tid = threadIdx.x;
  const int lane = tid & 63;
  const int l15 = lane & 15, g = lane >> 4;
  const int wid = tid >> 6, wr = wid >> 1, wc = wid & 1;
  const long m0 = (long)blockIdx.y * 128, n0 = (long)blockIdx.x * 128;

  f32x4 acc[4][4] = {};

  for (int k0 = 0; k0 < K; k0 += 32) {
#pragma unroll
    for (int p = 0; p < 2; ++p) {
      int e = p * 256 + tid;
      int row = e >> 2, col = (e & 3) * 8;
      gload_lds16(A + (m0 + row) * K + k0 + col, (char*)As + e * 16);
      gload_lds16(Bm + (n0 + row) * K + k0 + col, (char*)Bs + e * 16);
    }
    __syncthreads();
    bf16x8 af[4], bfr[4];
#pragma unroll
    for (int i = 0; i < 4; ++i) {
      af[i]  = bc8(*(const s16x8*)&As[(wr * 64 + i * 16 + l15) * 32 + g * 8]);
      bfr[i] = bc8(*(const s16x8*)&Bs[(wc * 64 + i * 16 + l15) * 32 + g * 8]);
    }
#pragma unroll
    for (int mi = 0; mi < 4; ++mi)
#pragma unroll
      for (int ni = 0; ni < 4; ++ni)
        acc[mi][ni] = mfma16x16x32(af[mi], bfr[ni], acc[mi][ni]);
    __syncthreads();
  }

#pragma unroll
  for (int mi = 0; mi < 4; ++mi)
#pragma unroll
    for (int ni = 0; ni < 4; ++ni) {
      long col = n0 + wc * 64 + ni * 16 + l15;
#pragma unroll
      for (int r = 0; r < 4; ++r) {
        long row = m0 + wr * 64 + mi * 16 + g * 4 + r;
        Cf[row * N + col] = acc[mi][ni][r] + bias[col];
      }
    }
}

// ---------- MFMA flash attention (2-phase pipelined, pre-transposed V) ----------
// grid (32, 64); 256 thr = 4 waves x 16 queries.
// st[kt][r] = S^T[key=kt*16+g*4+r][q=l15]; PV: O^T = V^T x P^T with
// A-frag from VtS (staged from pre-transposed Vt), B-frag from per-wave PS bounce.
__global__ __launch_bounds__(256) void k_flash(
    const unsigned short* __restrict__ Qh, const unsigned short* __restrict__ Ql,
    const unsigned short* __restrict__ Kh, const unsigned short* __restrict__ Kl,
    const unsigned short* __restrict__ Vt, unsigned short* __restrict__ o) {
  __shared__ unsigned short KhS[2][64 * 64];
  __shared__ unsigned short KlS[2][64 * 64];
  __shared__ unsigned short VtS[2][64 * 64];
  __shared__ unsigned short PS[4][16 * 64];
  const int tid = threadIdx.x;
  const int lane = tid & 63, wid = tid >> 6;
  const int l15 = lane & 15, g = lane >> 4;
  const int bh = blockIdx.y, b = bh >> 4, h = bh & 15;
  const int q0 = blockIdx.x * 64 + wid * 16;
  const long slab = (long)bh * 131072;

  const long qrow = slab + (long)(q0 + l15) * 64;
  bf16x8 qh0 = bc8(*(const s16x8*)&Qh[qrow + g * 8]);
  bf16x8 qh1 = bc8(*(const s16x8*)&Qh[qrow + 32 + g * 8]);
  bf16x8 ql0 = bc8(*(const s16x8*)&Ql[qrow + g * 8]);
  bf16x8 ql1 = bc8(*(const s16x8*)&Ql[qrow + 32 + g * 8]);

  f32x4 ovt[4] = {};
  float mrun = -1e30f, lrun = 0.f;

  // stage tile t into buffer buf (6 gloads/thread; dest linear, src swizzled)
  auto stage = [&](int buf, int t) {
    const int kv0 = t * 64;
#pragma unroll
    for (int p = 0; p < 2; ++p) {
      int u = p * 256 + tid;
      int row = u >> 3, cu = u & 7, c = cu ^ (row & 7);
      gload_lds16(Kh + slab + (long)(kv0 + row) * 64 + c * 8, (char*)&KhS[buf][0] + u * 16);
      gload_lds16(Kl + slab + (long)(kv0 + row) * 64 + c * 8, (char*)&KlS[buf][0] + u * 16);
      gload_lds16(Vt + slab + (long)row * 2048 + kv0 + c * 8, (char*)&VtS[buf][0] + u * 16);
    }
  };

  stage(0, 0);
  __syncthreads();   // implicit vmcnt(0) drain -> tile 0 resident

  for (int t = 0; t < 32; ++t) {
    const int cur = t & 1;
    if (t < 31) stage(cur ^ 1, t + 1);   // prefetch overlaps compute below

    // QK^T split: S = kh*qh + kh*ql + kl*qh  (fp32-accurate scores)
    f32x4 st[4];
#pragma unroll
    for (int kt = 0; kt < 4; ++kt) {
      f32x4 sacc = {};
#pragma unroll
      for (int kk = 0; kk < 2; ++kk) {
        int row = kt * 16 + l15;
        int uu = row * 8 + ((kk * 4 + g) ^ (row & 7));
        bf16x8 khf = bc8(*(const s16x8*)&KhS[cur][uu * 8]);
        bf16x8 klf = bc8(*(const s16x8*)&KlS[cur][uu * 8]);
        bf16x8 qhf = kk ? qh1 : qh0;
        bf16x8 qlf = kk ? ql1 : ql0;
        sacc = mfma16x16x32(khf, qhf, sacc);
        sacc = mfma16x16x32(khf, qlf, sacc);
        sacc = mfma16x16x32(klf, qhf, sacc);
      }
      st[kt] = sacc;
    }

    // online softmax (scale pre-folded into Q)
    float tmax = -1e30f;
#pragma unroll
    for (int kt = 0; kt < 4; ++kt)
#pragma unroll
      for (int r = 0; r < 4; ++r) tmax = fmaxf(tmax, st[kt][r]);
    tmax = fmaxf(tmax, __shfl_xor(tmax, 16));
    tmax = fmaxf(tmax, __shfl_xor(tmax, 32));
    float mnew = fmaxf(mrun, tmax);
    float corr = __expf(mrun - mnew);
    mrun = mnew;
    lrun *= corr;
#pragma unroll
    for (int dt = 0; dt < 4; ++dt) ovt[dt] *= corr;

    unsigned pb[4][2];
#pragma unroll
    for (int kt = 0; kt < 4; ++kt) {
      float p0 = __expf(st[kt][0] - mnew);
      float p1 = __expf(st[kt][1] - mnew);
      float p2 = __expf(st[kt][2] - mnew);
      float p3 = __expf(st[kt][3] - mnew);
      lrun += p0 + p1 + p2 + p3;
      pb[kt][0] = (unsigned)f2bf(p0) | ((unsigned)f2bf(p1) << 16);
      pb[kt][1] = (unsigned)f2bf(p2) | ((unsigned)f2bf(p3) << 16);
    }
    // P^T bounce to per-wave LDS (unit swizzled by q&7)
#pragma unroll
    for (int kt = 0; kt < 4; ++kt) {
      int up = ((kt * 2 + (g >> 1)) ^ (l15 & 7)) & 7;
      u32x2 w = {pb[kt][0], pb[kt][1]};
      *(u32x2*)&PS[wid][l15 * 64 + up * 8 + (g & 1) * 4] = w;
    }
    asm volatile("s_waitcnt lgkmcnt(0)" ::: "memory");
    __builtin_amdgcn_sched_barrier(0);

    // PV: O^T[d][q] += V^T-frag x P^T-frag
#pragma unroll
    for (int khalf = 0; khalf < 2; ++khalf) {
      int ub = (khalf * 4 + g) ^ (l15 & 7);
      bf16x8 pf = bc8(*(const s16x8*)&PS[wid][l15 * 64 + ub * 8]);
#pragma unroll
      for (int dt = 0; dt < 4; ++dt) {
        int d = dt * 16 + l15;
        int vv = d * 8 + ((khalf * 4 + g) ^ (d & 7));
        bf16x8 vf = bc8(*(const s16x8*)&VtS[cur][vv * 8]);
        ovt[dt] = mfma16x16x32(vf, pf, ovt[dt]);
      }
    }
    __syncthreads();   // one barrier/tile: drains prefetch, retires cur buffer
  }

  lrun += __shfl_xor(lrun, 16);
  lrun += __shfl_xor(lrun, 32);
  float rinv = 1.0f / lrun;
  long orow = ((long)(b * 2048 + q0 + l15)) * 1024 + h * 64;
#pragma unroll
  for (int dt = 0; dt < 4; ++dt) {
    ushort4 w4;
    w4.x = f2bf(ovt[dt][0] * rinv);
    w4.y = f2bf(ovt[dt][1] * rinv);
    w4.z = f2bf(ovt[dt][2] * rinv);
    w4.w = f2bf(ovt[dt][3] * rinv);
    *(ushort4*)&o[orow + dt * 16 + g * 4] = w4;
  }
}

// ---------- launcher ----------
extern "C" void kernel_launch(void* const* d_in, const int* in_sizes, int n_in,
                              void* d_out, int out_size, void* d_ws, size_t ws_size,
                              hipStream_t stream) {
  const float* x      = (const float*)d_in[0];
  const float* sin_t  = (const float*)d_in[1];
  const float* cos_t  = (const float*)d_in[2];
  const float* w_qkv  = (const float*)d_in[3];
  const float* w_proj = (const float*)d_in[4];
  const float* b_proj = (const float*)d_in[5];
  float* out = (float*)d_out;

  char* ws = (char*)d_ws;
  unsigned short* xb     = (unsigned short*)(ws);                 // 16 MiB
  unsigned short* wqkvb  = (unsigned short*)(ws + (16l << 20));   // 6 MiB
  unsigned short* wprojb = (unsigned short*)(ws + (22l << 20));   // 2 MiB
  unsigned short* Qh     = (unsigned short*)(ws + (24l << 20));   // 16 MiB
  unsigned short* Ql     = (unsigned short*)(ws + (40l << 20));   // 16 MiB
  unsigned short* Kh     = (unsigned short*)(ws + (56l << 20));   // 16 MiB
  unsigned short* Kl     = (unsigned short*)(ws + (72l << 20));   // 16 MiB
  unsigned short* Vb     = (unsigned short*)(ws + (88l << 20));   // 16 MiB
  unsigned short* Vt     = (unsigned short*)(ws + (104l << 20));  // 16 MiB
  unsigned short* ob     = xb;   // alias: xb dead after QKV GEMM

  k_f32_to_bf16<<<8192, 256, 0, stream>>>(x, xb, 8388608 / 4);
  k_f32_to_bf16<<<3072, 256, 0, stream>>>(w_qkv, wqkvb, 3145728 / 4);
  k_f32_to_bf16<<<1024, 256, 0, stream>>>(w_proj, wprojb, 1048576 / 4);

  k_gemm_qkv<<<dim3(24, 64), 256, 0, stream>>>(xb, wqkvb, Qh, Ql, Kh, Kl, Vb,
                                               sin_t, cos_t);
  k_vtrans<<<dim3(8, 64), 256, 0, stream>>>(Vb, Vt);
  k_flash<<<dim3(32, 64), 256, 0, stream>>>(Qh, Ql, Kh, Kl, Vt, ob);
  k_gemm_proj<<<dim3(8, 64), 256, 0, stream>>>(ob, wprojb, out, b_proj,
                                               8192, 1024, 1024);
}

// Round 8
// 310.008 us; speedup vs baseline: 1.1844x; 1.1844x over previous
//
#include <hip/hip_runtime.h>
#include <stdint.h>

// ---------- types ----------
typedef __bf16 bf16x8 __attribute__((ext_vector_type(8)));
typedef float f32x4 __attribute__((ext_vector_type(4)));
typedef short s16x8 __attribute__((ext_vector_type(8)));
typedef unsigned int u32x2 __attribute__((ext_vector_type(2)));

__device__ __forceinline__ unsigned short f2bf(float f) {
  unsigned u = __builtin_bit_cast(unsigned, f);
  u += 0x7fff + ((u >> 16) & 1);   // RNE
  return (unsigned short)(u >> 16);
}
__device__ __forceinline__ float bf2f(unsigned short b) {
  unsigned u = ((unsigned)b) << 16;
  return __builtin_bit_cast(float, u);
}
__device__ __forceinline__ float exp2i(float x) {    // v_exp_f32 = 2^x
  float r;
  asm("v_exp_f32 %0, %1" : "=v"(r) : "v"(x));
  return r;
}
__device__ __forceinline__ unsigned cvtpk(float lo, float hi) {  // 2xf32 -> packed bf16
  unsigned r;
  asm("v_cvt_pk_bf16_f32 %0, %1, %2" : "=v"(r) : "v"(lo), "v"(hi));
  return r;
}

__device__ __forceinline__ void gload_lds16(const void* g, void* l) {
  __builtin_amdgcn_global_load_lds(
      (const __attribute__((address_space(1))) unsigned int*)g,
      (__attribute__((address_space(3))) unsigned int*)l, 16, 0, 0);
}

__device__ __forceinline__ f32x4 mfma16x16x32(bf16x8 a, bf16x8 b, f32x4 c) {
  return __builtin_amdgcn_mfma_f32_16x16x32_bf16(a, b, c, 0, 0, 0);
}
__device__ __forceinline__ bf16x8 bc8(s16x8 v) { return __builtin_bit_cast(bf16x8, v); }

// ---------- fp32 -> bf16 convert ----------
__global__ void k_f32_to_bf16(const float* __restrict__ in,
                              unsigned short* __restrict__ out, int n4) {
  int i = blockIdx.x * blockDim.x + threadIdx.x;
  if (i < n4) {
    float4 v = ((const float4*)in)[i];
    ushort4 o;
    o.x = f2bf(v.x); o.y = f2bf(v.y); o.z = f2bf(v.z); o.w = f2bf(v.w);
    ((ushort4*)out)[i] = o;
  }
}

// ---------- QKV GEMM with fused RoPE + hi/lo-split epilogue ----------
// Q is pre-scaled by 0.125*log2(e) (fp32, before exact hi/lo split) so the
// flash softmax runs in exp2 domain with no per-element muls.
__global__ __launch_bounds__(256) void k_gemm_qkv(
    const unsigned short* __restrict__ A, const unsigned short* __restrict__ Bm,
    unsigned short* __restrict__ Qh, unsigned short* __restrict__ Ql,
    unsigned short* __restrict__ Kh, unsigned short* __restrict__ Kl,
    unsigned short* __restrict__ Vb,
    const float* __restrict__ sin_t, const float* __restrict__ cos_t) {
  const int M_K = 1024;
  __shared__ unsigned short As[128 * 32];
  __shared__ unsigned short Bs[128 * 32];
  const int tid = threadIdx.x;
  const int lane = tid & 63;
  const int l15 = lane & 15, g = lane >> 4;
  const int wid = tid >> 6, wr = wid >> 1, wc = wid & 1;
  const long m0 = (long)blockIdx.y * 128, n0 = (long)blockIdx.x * 128;

  f32x4 acc[4][4] = {};

  for (int k0 = 0; k0 < M_K; k0 += 32) {
#pragma unroll
    for (int p = 0; p < 2; ++p) {
      int e = p * 256 + tid;
      int row = e >> 2, col = (e & 3) * 8;
      gload_lds16(A + (m0 + row) * M_K + k0 + col, (char*)As + e * 16);
      gload_lds16(Bm + (n0 + row) * M_K + k0 + col, (char*)Bs + e * 16);
    }
    __syncthreads();
    bf16x8 af[4], bfr[4];
#pragma unroll
    for (int i = 0; i < 4; ++i) {
      af[i]  = bc8(*(const s16x8*)&As[(wr * 64 + i * 16 + l15) * 32 + g * 8]);
      bfr[i] = bc8(*(const s16x8*)&Bs[(wc * 64 + i * 16 + l15) * 32 + g * 8]);
    }
#pragma unroll
    for (int mi = 0; mi < 4; ++mi)
#pragma unroll
      for (int ni = 0; ni < 4; ++ni)
        acc[mi][ni] = mfma16x16x32(af[mi], bfr[ni], acc[mi][ni]);
    __syncthreads();
  }

  const int colbase = (int)n0 + wc * 64;
  const int s  = colbase >> 10;           // 0=q 1=k 2=v
  const int h  = (colbase >> 6) & 15;
  const float QSC = 0.125f * 1.44269504089f;   // fold 1/sqrt(D) * log2(e)
#pragma unroll
  for (int mi = 0; mi < 4; ++mi)
#pragma unroll
    for (int r = 0; r < 4; ++r) {
      long m = m0 + wr * 64 + mi * 16 + g * 4 + r;
      int b = (int)(m >> 11), n = (int)(m & 2047);
      long slab = ((long)(b * 16 + h)) * 131072 + (long)n * 64;
      float v0 = acc[mi][0][r], v1 = acc[mi][1][r];
      float v2 = acc[mi][2][r], v3 = acc[mi][3][r];
      if (s == 2) {
        Vb[slab + l15]      = f2bf(v0);
        Vb[slab + 16 + l15] = f2bf(v1);
        Vb[slab + 32 + l15] = f2bf(v2);
        Vb[slab + 48 + l15] = f2bf(v3);
      } else {
        float o0 = v0, o1 = v1, o2 = v2, o3 = v3;
        if (n >= 4) {
          const float* cs = cos_t + (long)(n - 4) * 64;
          const float* sn = sin_t + (long)(n - 4) * 64;
          float c0 = cs[l15], c1 = cs[16 + l15], c2 = cs[32 + l15], c3 = cs[48 + l15];
          float s0 = sn[l15], s1 = sn[16 + l15], s2 = sn[32 + l15], s3 = sn[48 + l15];
          float t0 = o0, t1 = o1;
          o0 = o0 * c0 - o2 * s0;  o1 = o1 * c1 - o3 * s1;
          o2 = o2 * c2 + t0 * s2;  o3 = o3 * c3 + t1 * s3;
        }
        if (s == 0) { o0 *= QSC; o1 *= QSC; o2 *= QSC; o3 *= QSC; }
        unsigned short* H = (s == 0) ? Qh : Kh;
        unsigned short* L = (s == 0) ? Ql : Kl;
        unsigned short h0 = f2bf(o0); H[slab + l15]      = h0; L[slab + l15]      = f2bf(o0 - bf2f(h0));
        unsigned short h1 = f2bf(o1); H[slab + 16 + l15] = h1; L[slab + 16 + l15] = f2bf(o1 - bf2f(h1));
        unsigned short h2 = f2bf(o2); H[slab + 32 + l15] = h2; L[slab + 32 + l15] = f2bf(o2 - bf2f(h2));
        unsigned short h3 = f2bf(o3); H[slab + 48 + l15] = h3; L[slab + 48 + l15] = f2bf(o3 - bf2f(h3));
      }
    }
}

// ---------- V transpose: Vb [bh][2048 n][64 d] -> Vt [bh][64 d][2048 n] ----------
__global__ __launch_bounds__(256) void k_vtrans(const unsigned short* __restrict__ Vb,
                                                unsigned short* __restrict__ Vt) {
  __shared__ unsigned short T[64 * 256];
  const int tid = threadIdx.x;
  const int bh = blockIdx.y;
  const int n0 = blockIdx.x * 256;
  const long slab = (long)bh * 131072;
#pragma unroll
  for (int it = 0; it < 8; ++it) {
    int u = it * 256 + tid;
    int key = u >> 3, dc = u & 7;
    s16x8 v = *(const s16x8*)&Vb[slab + (long)(n0 + key) * 64 + dc * 8];
#pragma unroll
    for (int i = 0; i < 8; ++i) {
      int d = dc * 8 + i;
      T[d * 256 + (key ^ (dc << 3))] = (unsigned short)v[i];
    }
  }
  __syncthreads();
#pragma unroll
  for (int it = 0; it < 8; ++it) {
    int w = it * 256 + tid;
    int d = w >> 5, nc = w & 31;
    int ncs = (nc & 24) | ((nc & 7) ^ (d >> 3));
    s16x8 v = *(const s16x8*)&T[d * 256 + ncs * 8];
    *(s16x8*)&Vt[slab + (long)d * 2048 + n0 + nc * 8] = v;
  }
}

// ---------- generic bf16 GEMM (final projection), f32 out + bias ----------
__global__ __launch_bounds__(256) void k_gemm_proj(
    const unsigned short* __restrict__ A, const unsigned short* __restrict__ Bm,
    float* __restrict__ Cf, const float* __restrict__ bias, int M, int N, int K) {
  __shared__ unsigned short As[128 * 32];
  __shared__ unsigned short Bs[128 * 32];
  const int tid = threadIdx.x;
  const int lane = tid & 63;
  const int l15 = lane & 15, g = lane >> 4;
  const int wid = tid >> 6, wr = wid >> 1, wc = wid & 1;
  const long m0 = (long)blockIdx.y * 128, n0 = (long)blockIdx.x * 128;

  f32x4 acc[4][4] = {};

  for (int k0 = 0; k0 < K; k0 += 32) {
#pragma unroll
    for (int p = 0; p < 2; ++p) {
      int e = p * 256 + tid;
      int row = e >> 2, col = (e & 3) * 8;
      gload_lds16(A + (m0 + row) * K + k0 + col, (char*)As + e * 16);
      gload_lds16(Bm + (n0 + row) * K + k0 + col, (char*)Bs + e * 16);
    }
    __syncthreads();
    bf16x8 af[4], bfr[4];
#pragma unroll
    for (int i = 0; i < 4; ++i) {
      af[i]  = bc8(*(const s16x8*)&As[(wr * 64 + i * 16 + l15) * 32 + g * 8]);
      bfr[i] = bc8(*(const s16x8*)&Bs[(wc * 64 + i * 16 + l15) * 32 + g * 8]);
    }
#pragma unroll
    for (int mi = 0; mi < 4; ++mi)
#pragma unroll
      for (int ni = 0; ni < 4; ++ni)
        acc[mi][ni] = mfma16x16x32(af[mi], bfr[ni], acc[mi][ni]);
    __syncthreads();
  }

#pragma unroll
  for (int mi = 0; mi < 4; ++mi)
#pragma unroll
    for (int ni = 0; ni < 4; ++ni) {
      long col = n0 + wc * 64 + ni * 16 + l15;
#pragma unroll
      for (int r = 0; r < 4; ++r) {
        long row = m0 + wr * 64 + mi * 16 + g * 4 + r;
        Cf[row * N + col] = acc[mi][ni][r] + bias[col];
      }
    }
}

// ---------- MFMA flash attention ----------
// K double-buffered, V single-buffered (48 KiB LDS -> 3 blocks/CU).
// exp2-domain softmax (scale folded into Q), cvt_pk P-pack, defer-max THR=8.
// Counted vmcnt(4) before PV leaves the 4 K-prefetch loads in flight.
__global__ __launch_bounds__(256) void k_flash(
    const unsigned short* __restrict__ Qh, const unsigned short* __restrict__ Ql,
    const unsigned short* __restrict__ Kh, const unsigned short* __restrict__ Kl,
    const unsigned short* __restrict__ Vt, unsigned short* __restrict__ o) {
  __shared__ unsigned short KhS[2][64 * 64];
  __shared__ unsigned short KlS[2][64 * 64];
  __shared__ unsigned short VtS[64 * 64];
  __shared__ unsigned short PS[4][16 * 64];
  const int tid = threadIdx.x;
  const int lane = tid & 63, wid = tid >> 6;
  const int l15 = lane & 15, g = lane >> 4;
  const int bh = blockIdx.y, b = bh >> 4, h = bh & 15;
  const int q0 = blockIdx.x * 64 + wid * 16;
  const long slab = (long)bh * 131072;

  const long qrow = slab + (long)(q0 + l15) * 64;
  bf16x8 qh0 = bc8(*(const s16x8*)&Qh[qrow + g * 8]);
  bf16x8 qh1 = bc8(*(const s16x8*)&Qh[qrow + 32 + g * 8]);
  bf16x8 ql0 = bc8(*(const s16x8*)&Ql[qrow + g * 8]);
  bf16x8 ql1 = bc8(*(const s16x8*)&Ql[qrow + 32 + g * 8]);

  f32x4 ovt[4] = {};
  float mrun = -1e30f, lrun = 0.f;

  auto stageK = [&](int buf, int t) {
    const int kv0 = t * 64;
#pragma unroll
    for (int p = 0; p < 2; ++p) {
      int u = p * 256 + tid;
      int row = u >> 3, cu = u & 7, c = cu ^ (row & 7);
      gload_lds16(Kh + slab + (long)(kv0 + row) * 64 + c * 8, (char*)&KhS[buf][0] + u * 16);
      gload_lds16(Kl + slab + (long)(kv0 + row) * 64 + c * 8, (char*)&KlS[buf][0] + u * 16);
    }
  };
  auto stageV = [&](int t) {
    const int kv0 = t * 64;
#pragma unroll
    for (int p = 0; p < 2; ++p) {
      int u = p * 256 + tid;
      int row = u >> 3, cu = u & 7, c = cu ^ (row & 7);
      gload_lds16(Vt + slab + (long)row * 2048 + kv0 + c * 8, (char*)&VtS[0] + u * 16);
    }
  };

  stageK(0, 0);
  stageV(0);
  __syncthreads();                 // tile 0 resident

  for (int t = 0; t < 32; ++t) {
    const int cur = t & 1;
    if (t < 31) stageK(cur ^ 1, t + 1);       // overlaps whole tile body

    // QK^T split: S = kh*qh + kh*ql + kl*qh  (fp32-accurate, exp2-domain)
    f32x4 st[4];
    __builtin_amdgcn_s_setprio(1);
#pragma unroll
    for (int kt = 0; kt < 4; ++kt) {
      f32x4 sacc = {};
#pragma unroll
      for (int kk = 0; kk < 2; ++kk) {
        int row = kt * 16 + l15;
        int uu = row * 8 + ((kk * 4 + g) ^ (row & 7));
        bf16x8 khf = bc8(*(const s16x8*)&KhS[cur][uu * 8]);
        bf16x8 klf = bc8(*(const s16x8*)&KlS[cur][uu * 8]);
        bf16x8 qhf = kk ? qh1 : qh0;
        bf16x8 qlf = kk ? ql1 : ql0;
        sacc = mfma16x16x32(khf, qhf, sacc);
        sacc = mfma16x16x32(khf, qlf, sacc);
        sacc = mfma16x16x32(klf, qhf, sacc);
      }
      st[kt] = sacc;
    }
    __builtin_amdgcn_s_setprio(0);

    // per-query tile max (tree in-lane, then across the 4 g-lanes)
    float m0a = fmaxf(fmaxf(st[0][0], st[0][1]), fmaxf(st[0][2], st[0][3]));
    float m1a = fmaxf(fmaxf(st[1][0], st[1][1]), fmaxf(st[1][2], st[1][3]));
    float m2a = fmaxf(fmaxf(st[2][0], st[2][1]), fmaxf(st[2][2], st[2][3]));
    float m3a = fmaxf(fmaxf(st[3][0], st[3][1]), fmaxf(st[3][2], st[3][3]));
    float tmax = fmaxf(fmaxf(m0a, m1a), fmaxf(m2a, m3a));
    tmax = fmaxf(tmax, __shfl_xor(tmax, 16));
    tmax = fmaxf(tmax, __shfl_xor(tmax, 32));

    // defer-max: only rescale when tile max exceeds running max by >8 (2^8 bound)
    if (!__all(tmax <= mrun + 8.f)) {
      float mnew = fmaxf(mrun, tmax);
      float corr = exp2i(mrun - mnew);
      lrun *= corr;
#pragma unroll
      for (int dt = 0; dt < 4; ++dt) ovt[dt] *= corr;
      mrun = mnew;
    }

    unsigned pb[4][2];
#pragma unroll
    for (int kt = 0; kt < 4; ++kt) {
      float p0 = exp2i(st[kt][0] - mrun);
      float p1 = exp2i(st[kt][1] - mrun);
      float p2 = exp2i(st[kt][2] - mrun);
      float p3 = exp2i(st[kt][3] - mrun);
      lrun += (p0 + p1) + (p2 + p3);
      pb[kt][0] = cvtpk(p0, p1);
      pb[kt][1] = cvtpk(p2, p3);
    }
    // P^T bounce to per-wave LDS (unit swizzled by q&7)
#pragma unroll
    for (int kt = 0; kt < 4; ++kt) {
      int up = ((kt * 2 + (g >> 1)) ^ (l15 & 7)) & 7;
      u32x2 w = {pb[kt][0], pb[kt][1]};
      *(u32x2*)&PS[wid][l15 * 64 + up * 8 + (g & 1) * 4] = w;
    }
    asm volatile("s_waitcnt lgkmcnt(0)" ::: "memory");
    __builtin_amdgcn_sched_barrier(0);
    if (t < 31) asm volatile("s_waitcnt vmcnt(4)" ::: "memory");  // V landed, K in flight
    else        asm volatile("s_waitcnt vmcnt(0)" ::: "memory");
    __builtin_amdgcn_sched_barrier(0);

    // PV: O^T[d][q] += V^T-frag x P^T-frag
    __builtin_amdgcn_s_setprio(1);
#pragma unroll
    for (int khalf = 0; khalf < 2; ++khalf) {
      int ub = (khalf * 4 + g) ^ (l15 & 7);
      bf16x8 pf = bc8(*(const s16x8*)&PS[wid][l15 * 64 + ub * 8]);
#pragma unroll
      for (int dt = 0; dt < 4; ++dt) {
        int d = dt * 16 + l15;
        int vv = d * 8 + ((khalf * 4 + g) ^ (d & 7));
        bf16x8 vf = bc8(*(const s16x8*)&VtS[vv * 8]);
        ovt[dt] = mfma16x16x32(vf, pf, ovt[dt]);
      }
    }
    __builtin_amdgcn_s_setprio(0);
    __syncthreads();               // all PV(t) reads done; drains K(t+1) prefetch
    if (t < 31) stageV(t + 1);     // overlaps next tile's QK; guarded by vmcnt(4)
  }

  lrun += __shfl_xor(lrun, 16);
  lrun += __shfl_xor(lrun, 32);
  float rinv = 1.0f / lrun;
  long orow = ((long)(b * 2048 + q0 + l15)) * 1024 + h * 64;
#pragma unroll
  for (int dt = 0; dt < 4; ++dt) {
    ushort4 w4;
    w4.x = f2bf(ovt[dt][0] * rinv);
    w4.y = f2bf(ovt[dt][1] * rinv);
    w4.z = f2bf(ovt[dt][2] * rinv);
    w4.w = f2bf(ovt[dt][3] * rinv);
    *(ushort4*)&o[orow + dt * 16 + g * 4] = w4;
  }
}

// ---------- launcher ----------
extern "C" void kernel_launch(void* const* d_in, const int* in_sizes, int n_in,
                              void* d_out, int out_size, void* d_ws, size_t ws_size,
                              hipStream_t stream) {
  const float* x      = (const float*)d_in[0];
  const float* sin_t  = (const float*)d_in[1];
  const float* cos_t  = (const float*)d_in[2];
  const float* w_qkv  = (const float*)d_in[3];
  const float* w_proj = (const float*)d_in[4];
  const float* b_proj = (const float*)d_in[5];
  float* out = (float*)d_out;

  char* ws = (char*)d_ws;
  unsigned short* xb     = (unsigned short*)(ws);                 // 16 MiB
  unsigned short* wqkvb  = (unsigned short*)(ws + (16l << 20));   // 6 MiB
  unsigned short* wprojb = (unsigned short*)(ws + (22l << 20));   // 2 MiB
  unsigned short* Qh     = (unsigned short*)(ws + (24l << 20));   // 16 MiB
  unsigned short* Ql     = (unsigned short*)(ws + (40l << 20));   // 16 MiB
  unsigned short* Kh     = (unsigned short*)(ws + (56l << 20));   // 16 MiB
  unsigned short* Kl     = (unsigned short*)(ws + (72l << 20));   // 16 MiB
  unsigned short* Vb     = (unsigned short*)(ws + (88l << 20));   // 16 MiB
  unsigned short* Vt     = (unsigned short*)(ws + (104l << 20));  // 16 MiB
  unsigned short* ob     = xb;   // alias: xb dead after QKV GEMM

  k_f32_to_bf16<<<8192, 256, 0, stream>>>(x, xb, 8388608 / 4);
  k_f32_to_bf16<<<3072, 256, 0, stream>>>(w_qkv, wqkvb, 3145728 / 4);
  k_f32_to_bf16<<<1024, 256, 0, stream>>>(w_proj, wprojb, 1048576 / 4);

  k_gemm_qkv<<<dim3(24, 64), 256, 0, stream>>>(xb, wqkvb, Qh, Ql, Kh, Kl, Vb,
                                               sin_t, cos_t);
  k_vtrans<<<dim3(8, 64), 256, 0, stream>>>(Vb, Vt);
  k_flash<<<dim3(32, 64), 256, 0, stream>>>(Qh, Ql, Kh, Kl, Vt, ob);
  k_gemm_proj<<<dim3(8, 64), 256, 0, stream>>>(ob, wprojb, out, b_proj,
                                               8192, 1024, 1024);
}

// Round 10
// 269.233 us; speedup vs baseline: 1.3638x; 1.1514x over previous
//
#include <hip/hip_runtime.h>
#include <stdint.h>

// ---------- types ----------
typedef __bf16 bf16x8 __attribute__((ext_vector_type(8)));
typedef _Float16 f16x8 __attribute__((ext_vector_type(8)));
typedef float f32x4 __attribute__((ext_vector_type(4)));
typedef short s16x8 __attribute__((ext_vector_type(8)));
typedef unsigned int u32x2 __attribute__((ext_vector_type(2)));

__device__ __forceinline__ unsigned short f2bf(float f) {
  unsigned u = __builtin_bit_cast(unsigned, f);
  u += 0x7fff + ((u >> 16) & 1);   // RNE
  return (unsigned short)(u >> 16);
}
__device__ __forceinline__ unsigned short f2h(float f) {
  return __builtin_bit_cast(unsigned short, (_Float16)f);
}
__device__ __forceinline__ float exp2i(float x) {    // v_exp_f32 = 2^x
  float r;
  asm("v_exp_f32 %0, %1" : "=v"(r) : "v"(x));
  return r;
}
__device__ __forceinline__ unsigned cvtpkh(float lo, float hi) {  // 2xf32 -> packed fp16
  auto r = __builtin_amdgcn_cvt_pkrtz(lo, hi);   // __fp16 ext_vector_type(2)
  return __builtin_bit_cast(unsigned, r);
}

__device__ __forceinline__ void gload_lds16(const void* g, void* l) {
  __builtin_amdgcn_global_load_lds(
      (const __attribute__((address_space(1))) unsigned int*)g,
      (__attribute__((address_space(3))) unsigned int*)l, 16, 0, 0);
}

__device__ __forceinline__ f32x4 mfma_bf(bf16x8 a, bf16x8 b, f32x4 c) {
  return __builtin_amdgcn_mfma_f32_16x16x32_bf16(a, b, c, 0, 0, 0);
}
__device__ __forceinline__ f32x4 mfma_h(f16x8 a, f16x8 b, f32x4 c) {
  return __builtin_amdgcn_mfma_f32_16x16x32_f16(a, b, c, 0, 0, 0);
}
__device__ __forceinline__ bf16x8 bc8(s16x8 v) { return __builtin_bit_cast(bf16x8, v); }
__device__ __forceinline__ f16x8 hc8(s16x8 v) { return __builtin_bit_cast(f16x8, v); }

// ---------- fp32 -> bf16 convert (x, w_qkv, w_proj in one launch) ----------
__global__ void k_cvt_all(const float* __restrict__ x, const float* __restrict__ wq,
                          const float* __restrict__ wp,
                          unsigned short* __restrict__ xb,
                          unsigned short* __restrict__ wqb,
                          unsigned short* __restrict__ wpb) {
  int i = blockIdx.x * blockDim.x + threadIdx.x;
  const float* in; unsigned short* out; int j = i;
  if (i < 2097152)        { in = x;  out = xb;  }
  else if (i < 2883584)   { in = wq; out = wqb; j = i - 2097152; }
  else                    { in = wp; out = wpb; j = i - 2883584; }
  float4 v = ((const float4*)in)[j];
  ushort4 o;
  o.x = f2bf(v.x); o.y = f2bf(v.y); o.z = f2bf(v.z); o.w = f2bf(v.w);
  ((ushort4*)out)[j] = o;
}

// ---------- QKV GEMM with fused RoPE + fp16 pack epilogue ----------
// Q pre-scaled by 0.125*log2(e) in fp32 -> flash softmax runs in exp2 domain.
// Outputs: Qf, Kf, Vb as fp16 slabs [B*H, N, D].
__global__ __launch_bounds__(256) void k_gemm_qkv(
    const unsigned short* __restrict__ A, const unsigned short* __restrict__ Bm,
    unsigned short* __restrict__ Qf, unsigned short* __restrict__ Kf,
    unsigned short* __restrict__ Vb,
    const float* __restrict__ sin_t, const float* __restrict__ cos_t) {
  const int M_K = 1024;
  __shared__ unsigned short As[128 * 32];
  __shared__ unsigned short Bs[128 * 32];
  const int tid = threadIdx.x;
  const int lane = tid & 63;
  const int l15 = lane & 15, g = lane >> 4;
  const int wid = tid >> 6, wr = wid >> 1, wc = wid & 1;
  const long m0 = (long)blockIdx.y * 128, n0 = (long)blockIdx.x * 128;

  f32x4 acc[4][4] = {};

  for (int k0 = 0; k0 < M_K; k0 += 32) {
#pragma unroll
    for (int p = 0; p < 2; ++p) {
      int e = p * 256 + tid;
      int row = e >> 2, col = (e & 3) * 8;
      gload_lds16(A + (m0 + row) * M_K + k0 + col, (char*)As + e * 16);
      gload_lds16(Bm + (n0 + row) * M_K + k0 + col, (char*)Bs + e * 16);
    }
    __syncthreads();
    bf16x8 af[4], bfr[4];
#pragma unroll
    for (int i = 0; i < 4; ++i) {
      af[i]  = bc8(*(const s16x8*)&As[(wr * 64 + i * 16 + l15) * 32 + g * 8]);
      bfr[i] = bc8(*(const s16x8*)&Bs[(wc * 64 + i * 16 + l15) * 32 + g * 8]);
    }
#pragma unroll
    for (int mi = 0; mi < 4; ++mi)
#pragma unroll
      for (int ni = 0; ni < 4; ++ni)
        acc[mi][ni] = mfma_bf(af[mi], bfr[ni], acc[mi][ni]);
    __syncthreads();
  }

  const int colbase = (int)n0 + wc * 64;
  const int s  = colbase >> 10;           // 0=q 1=k 2=v
  const int h  = (colbase >> 6) & 15;
  const float QSC = 0.125f * 1.44269504089f;
#pragma unroll
  for (int mi = 0; mi < 4; ++mi)
#pragma unroll
    for (int r = 0; r < 4; ++r) {
      long m = m0 + wr * 64 + mi * 16 + g * 4 + r;
      int b = (int)(m >> 11), n = (int)(m & 2047);
      long slab = ((long)(b * 16 + h)) * 131072 + (long)n * 64;
      float v0 = acc[mi][0][r], v1 = acc[mi][1][r];
      float v2 = acc[mi][2][r], v3 = acc[mi][3][r];
      if (s == 2) {
        Vb[slab + l15]      = f2h(v0);
        Vb[slab + 16 + l15] = f2h(v1);
        Vb[slab + 32 + l15] = f2h(v2);
        Vb[slab + 48 + l15] = f2h(v3);
      } else {
        float o0 = v0, o1 = v1, o2 = v2, o3 = v3;
        if (n >= 4) {
          const float* cs = cos_t + (long)(n - 4) * 64;
          const float* sn = sin_t + (long)(n - 4) * 64;
          float c0 = cs[l15], c1 = cs[16 + l15], c2 = cs[32 + l15], c3 = cs[48 + l15];
          float s0 = sn[l15], s1 = sn[16 + l15], s2 = sn[32 + l15], s3 = sn[48 + l15];
          float t0 = o0, t1 = o1;
          o0 = o0 * c0 - o2 * s0;  o1 = o1 * c1 - o3 * s1;
          o2 = o2 * c2 + t0 * s2;  o3 = o3 * c3 + t1 * s3;
        }
        if (s == 0) { o0 *= QSC; o1 *= QSC; o2 *= QSC; o3 *= QSC; }
        unsigned short* H = (s == 0) ? Qf : Kf;
        H[slab + l15]      = f2h(o0);
        H[slab + 16 + l15] = f2h(o1);
        H[slab + 32 + l15] = f2h(o2);
        H[slab + 48 + l15] = f2h(o3);
      }
    }
}

// ---------- V transpose: Vb [bh][2048 n][64 d] -> Vt [bh][64 d][2048 n] ----------
// (16-bit type agnostic)
__global__ __launch_bounds__(256) void k_vtrans(const unsigned short* __restrict__ Vb,
                                                unsigned short* __restrict__ Vt) {
  __shared__ unsigned short T[64 * 256];
  const int tid = threadIdx.x;
  const int bh = blockIdx.y;
  const int n0 = blockIdx.x * 256;
  const long slab = (long)bh * 131072;
#pragma unroll
  for (int it = 0; it < 8; ++it) {
    int u = it * 256 + tid;
    int key = u >> 3, dc = u & 7;
    s16x8 v = *(const s16x8*)&Vb[slab + (long)(n0 + key) * 64 + dc * 8];
#pragma unroll
    for (int i = 0; i < 8; ++i) {
      int d = dc * 8 + i;
      T[d * 256 + (key ^ (dc << 3))] = (unsigned short)v[i];
    }
  }
  __syncthreads();
#pragma unroll
  for (int it = 0; it < 8; ++it) {
    int w = it * 256 + tid;
    int d = w >> 5, nc = w & 31;
    int ncs = (nc & 24) | ((nc & 7) ^ (d >> 3));
    s16x8 v = *(const s16x8*)&T[d * 256 + ncs * 8];
    *(s16x8*)&Vt[slab + (long)d * 2048 + n0 + nc * 8] = v;
  }
}

// ---------- generic bf16 GEMM (final projection), f32 out + bias ----------
__global__ __launch_bounds__(256) void k_gemm_proj(
    const unsigned short* __restrict__ A, const unsigned short* __restrict__ Bm,
    float* __restrict__ Cf, const float* __restrict__ bias, int M, int N, int K) {
  __shared__ unsigned short As[128 * 32];
  __shared__ unsigned short Bs[128 * 32];
  const int tid = threadIdx.x;
  const int lane = tid & 63;
  const int l15 = lane & 15, g = lane >> 4;
  const int wid = tid >> 6, wr = wid >> 1, wc = wid & 1;
  const long m0 = (long)blockIdx.y * 128, n0 = (long)blockIdx.x * 128;

  f32x4 acc[4][4] = {};

  for (int k0 = 0; k0 < K; k0 += 32) {
#pragma unroll
    for (int p = 0; p < 2; ++p) {
      int e = p * 256 + tid;
      int row = e >> 2, col = (e & 3) * 8;
      gload_lds16(A + (m0 + row) * K + k0 + col, (char*)As + e * 16);
      gload_lds16(Bm + (n0 + row) * K + k0 + col, (char*)Bs + e * 16);
    }
    __syncthreads();
    bf16x8 af[4], bfr[4];
#pragma unroll
    for (int i = 0; i < 4; ++i) {
      af[i]  = bc8(*(const s16x8*)&As[(wr * 64 + i * 16 + l15) * 32 + g * 8]);
      bfr[i] = bc8(*(const s16x8*)&Bs[(wc * 64 + i * 16 + l15) * 32 + g * 8]);
    }
#pragma unroll
    for (int mi = 0; mi < 4; ++mi)
#pragma unroll
      for (int ni = 0; ni < 4; ++ni)
        acc[mi][ni] = mfma_bf(af[mi], bfr[ni], acc[mi][ni]);
    __syncthreads();
  }

#pragma unroll
  for (int mi = 0; mi < 4; ++mi)
#pragma unroll
    for (int ni = 0; ni < 4; ++ni) {
      long col = n0 + wc * 64 + ni * 16 + l15;
#pragma unroll
      for (int r = 0; r < 4; ++r) {
        long row = m0 + wr * 64 + mi * 16 + g * 4 + r;
        Cf[row * N + col] = acc[mi][ni][r] + bias[col];
      }
    }
}

// ---------- MFMA flash attention (fp16 Q/K/V) ----------
// K double-buffered (16 KiB), V single (8 KiB), PS (8 KiB) -> 32 KiB, 5 blk/CU.
// exp2-domain softmax, cvt_pkrtz P-pack, defer-max THR=8, counted vmcnt.
__global__ __launch_bounds__(256) void k_flash(
    const unsigned short* __restrict__ Qf, const unsigned short* __restrict__ Kf,
    const unsigned short* __restrict__ Vt, unsigned short* __restrict__ o) {
  __shared__ unsigned short KS[2][64 * 64];
  __shared__ unsigned short VtS[64 * 64];
  __shared__ unsigned short PS[4][16 * 64];
  const int tid = threadIdx.x;
  const int lane = tid & 63, wid = tid >> 6;
  const int l15 = lane & 15, g = lane >> 4;
  const int bh = blockIdx.y, b = bh >> 4, h = bh & 15;
  const int q0 = blockIdx.x * 64 + wid * 16;
  const long slab = (long)bh * 131072;

  const long qrow = slab + (long)(q0 + l15) * 64;
  f16x8 qf0 = hc8(*(const s16x8*)&Qf[qrow + g * 8]);
  f16x8 qf1 = hc8(*(const s16x8*)&Qf[qrow + 32 + g * 8]);

  f32x4 ovt[4] = {};
  float mrun = -1e30f, lrun = 0.f;

  auto stageK = [&](int buf, int t) {
    const int kv0 = t * 64;
#pragma unroll
    for (int p = 0; p < 2; ++p) {
      int u = p * 256 + tid;
      int row = u >> 3, cu = u & 7, c = cu ^ (row & 7);
      gload_lds16(Kf + slab + (long)(kv0 + row) * 64 + c * 8, (char*)&KS[buf][0] + u * 16);
    }
  };
  auto stageV = [&](int t) {
    const int kv0 = t * 64;
#pragma unroll
    for (int p = 0; p < 2; ++p) {
      int u = p * 256 + tid;
      int row = u >> 3, cu = u & 7, c = cu ^ (row & 7);
      gload_lds16(Vt + slab + (long)row * 2048 + kv0 + c * 8, (char*)&VtS[0] + u * 16);
    }
  };

  stageK(0, 0);
  stageV(0);
  __syncthreads();                 // tile 0 resident

  for (int t = 0; t < 32; ++t) {
    const int cur = t & 1;
    if (t < 31) stageK(cur ^ 1, t + 1);       // overlaps whole tile body

    // QK^T (fp16, exp2-domain, scale pre-folded into Q)
    f32x4 st[4];
    __builtin_amdgcn_s_setprio(1);
#pragma unroll
    for (int kt = 0; kt < 4; ++kt) {
      f32x4 sacc = {};
#pragma unroll
      for (int kk = 0; kk < 2; ++kk) {
        int row = kt * 16 + l15;
        int uu = row * 8 + ((kk * 4 + g) ^ (row & 7));
        f16x8 kf = hc8(*(const s16x8*)&KS[cur][uu * 8]);
        sacc = mfma_h(kf, kk ? qf1 : qf0, sacc);
      }
      st[kt] = sacc;
    }
    __builtin_amdgcn_s_setprio(0);

    // per-query tile max
    float m0a = fmaxf(fmaxf(st[0][0], st[0][1]), fmaxf(st[0][2], st[0][3]));
    float m1a = fmaxf(fmaxf(st[1][0], st[1][1]), fmaxf(st[1][2], st[1][3]));
    float m2a = fmaxf(fmaxf(st[2][0], st[2][1]), fmaxf(st[2][2], st[2][3]));
    float m3a = fmaxf(fmaxf(st[3][0], st[3][1]), fmaxf(st[3][2], st[3][3]));
    float tmax = fmaxf(fmaxf(m0a, m1a), fmaxf(m2a, m3a));
    tmax = fmaxf(tmax, __shfl_xor(tmax, 16));
    tmax = fmaxf(tmax, __shfl_xor(tmax, 32));

    // defer-max (THR=8 in log2 units: P bounded by 2^8, fp16-safe)
    if (!__all(tmax <= mrun + 8.f)) {
      float mnew = fmaxf(mrun, tmax);
      float corr = exp2i(mrun - mnew);
      lrun *= corr;
#pragma unroll
      for (int dt = 0; dt < 4; ++dt) ovt[dt] *= corr;
      mrun = mnew;
    }

    unsigned pb[4][2];
#pragma unroll
    for (int kt = 0; kt < 4; ++kt) {
      float p0 = exp2i(st[kt][0] - mrun);
      float p1 = exp2i(st[kt][1] - mrun);
      float p2 = exp2i(st[kt][2] - mrun);
      float p3 = exp2i(st[kt][3] - mrun);
      lrun += (p0 + p1) + (p2 + p3);
      pb[kt][0] = cvtpkh(p0, p1);
      pb[kt][1] = cvtpkh(p2, p3);
    }
    // P^T bounce to per-wave LDS (unit swizzled by q&7)
#pragma unroll
    for (int kt = 0; kt < 4; ++kt) {
      int up = ((kt * 2 + (g >> 1)) ^ (l15 & 7)) & 7;
      u32x2 w = {pb[kt][0], pb[kt][1]};
      *(u32x2*)&PS[wid][l15 * 64 + up * 8 + (g & 1) * 4] = w;
    }
    asm volatile("s_waitcnt lgkmcnt(0)" ::: "memory");
    __builtin_amdgcn_sched_barrier(0);
    if (t < 31) asm volatile("s_waitcnt vmcnt(2)" ::: "memory");  // V landed, K(t+1) in flight
    else        asm volatile("s_waitcnt vmcnt(0)" ::: "memory");
    __builtin_amdgcn_sched_barrier(0);

    // PV: O^T[d][q] += V^T-frag x P^T-frag
    __builtin_amdgcn_s_setprio(1);
#pragma unroll
    for (int khalf = 0; khalf < 2; ++khalf) {
      int ub = (khalf * 4 + g) ^ (l15 & 7);
      f16x8 pf = hc8(*(const s16x8*)&PS[wid][l15 * 64 + ub * 8]);
#pragma unroll
      for (int dt = 0; dt < 4; ++dt) {
        int d = dt * 16 + l15;
        int vv = d * 8 + ((khalf * 4 + g) ^ (d & 7));
        f16x8 vf = hc8(*(const s16x8*)&VtS[vv * 8]);
        ovt[dt] = mfma_h(vf, pf, ovt[dt]);
      }
    }
    __builtin_amdgcn_s_setprio(0);
    __syncthreads();               // PV(t) reads done; drains K(t+1)
    if (t < 31) stageV(t + 1);     // overlaps next tile's QK
  }

  lrun += __shfl_xor(lrun, 16);
  lrun += __shfl_xor(lrun, 32);
  float rinv = 1.0f / lrun;
  long orow = ((long)(b * 2048 + q0 + l15)) * 1024 + h * 64;
#pragma unroll
  for (int dt = 0; dt < 4; ++dt) {
    ushort4 w4;
    w4.x = f2bf(ovt[dt][0] * rinv);
    w4.y = f2bf(ovt[dt][1] * rinv);
    w4.z = f2bf(ovt[dt][2] * rinv);
    w4.w = f2bf(ovt[dt][3] * rinv);
    *(ushort4*)&o[orow + dt * 16 + g * 4] = w4;
  }
}

// ---------- launcher ----------
extern "C" void kernel_launch(void* const* d_in, const int* in_sizes, int n_in,
                              void* d_out, int out_size, void* d_ws, size_t ws_size,
                              hipStream_t stream) {
  const float* x      = (const float*)d_in[0];
  const float* sin_t  = (const float*)d_in[1];
  const float* cos_t  = (const float*)d_in[2];
  const float* w_qkv  = (const float*)d_in[3];
  const float* w_proj = (const float*)d_in[4];
  const float* b_proj = (const float*)d_in[5];
  float* out = (float*)d_out;

  char* ws = (char*)d_ws;
  unsigned short* xb     = (unsigned short*)(ws);                 // 16 MiB
  unsigned short* wqkvb  = (unsigned short*)(ws + (16l << 20));   // 6 MiB
  unsigned short* wprojb = (unsigned short*)(ws + (22l << 20));   // 2 MiB
  unsigned short* Qf     = (unsigned short*)(ws + (24l << 20));   // 16 MiB
  unsigned short* Kf     = (unsigned short*)(ws + (40l << 20));   // 16 MiB
  unsigned short* Vb     = (unsigned short*)(ws + (56l << 20));   // 16 MiB
  unsigned short* Vt     = (unsigned short*)(ws + (72l << 20));   // 16 MiB
  unsigned short* ob     = xb;   // alias: xb dead after QKV GEMM

  k_cvt_all<<<12288, 256, 0, stream>>>(x, w_qkv, w_proj, xb, wqkvb, wprojb);

  k_gemm_qkv<<<dim3(24, 64), 256, 0, stream>>>(xb, wqkvb, Qf, Kf, Vb,
                                               sin_t, cos_t);
  k_vtrans<<<dim3(8, 64), 256, 0, stream>>>(Vb, Vt);
  k_flash<<<dim3(32, 64), 256, 0, stream>>>(Qf, Kf, Vt, ob);
  k_gemm_proj<<<dim3(8, 64), 256, 0, stream>>>(ob, wprojb, out, b_proj,
                                               8192, 1024, 1024);
}

// Round 12
// 266.571 us; speedup vs baseline: 1.3774x; 1.0100x over previous
//
#include <hip/hip_runtime.h>
#include <stdint.h>

// ---------- types ----------
typedef __bf16 bf16x8 __attribute__((ext_vector_type(8)));
typedef _Float16 f16x8 __attribute__((ext_vector_type(8)));
typedef float f32x4 __attribute__((ext_vector_type(4)));
typedef short s16x8 __attribute__((ext_vector_type(8)));
typedef short s16x4 __attribute__((ext_vector_type(4)));
typedef unsigned int u32x4 __attribute__((ext_vector_type(4)));

__device__ __forceinline__ unsigned short f2bf(float f) {
  unsigned u = __builtin_bit_cast(unsigned, f);
  u += 0x7fff + ((u >> 16) & 1);   // RNE
  return (unsigned short)(u >> 16);
}
__device__ __forceinline__ unsigned short f2h(float f) {
  return __builtin_bit_cast(unsigned short, (_Float16)f);
}
__device__ __forceinline__ float exp2i(float x) {    // v_exp_f32 = 2^x
  float r;
  asm("v_exp_f32 %0, %1" : "=v"(r) : "v"(x));
  return r;
}
__device__ __forceinline__ unsigned cvtpkh(float lo, float hi) {  // 2xf32 -> packed fp16
  auto r = __builtin_amdgcn_cvt_pkrtz(lo, hi);
  return __builtin_bit_cast(unsigned, r);
}

__device__ __forceinline__ void gload_lds16(const void* g, void* l) {
  __builtin_amdgcn_global_load_lds(
      (const __attribute__((address_space(1))) unsigned int*)g,
      (__attribute__((address_space(3))) unsigned int*)l, 16, 0, 0);
}

__device__ __forceinline__ f32x4 mfma_bf(bf16x8 a, bf16x8 b, f32x4 c) {
  return __builtin_amdgcn_mfma_f32_16x16x32_bf16(a, b, c, 0, 0, 0);
}
__device__ __forceinline__ f32x4 mfma_h(f16x8 a, f16x8 b, f32x4 c) {
  return __builtin_amdgcn_mfma_f32_16x16x32_f16(a, b, c, 0, 0, 0);
}
__device__ __forceinline__ bf16x8 bc8(s16x8 v) { return __builtin_bit_cast(bf16x8, v); }
__device__ __forceinline__ f16x8 hc8(s16x8 v) { return __builtin_bit_cast(f16x8, v); }

// ---------- fp32 -> bf16 convert (x, w_qkv, w_proj in one launch) ----------
__global__ void k_cvt_all(const float* __restrict__ x, const float* __restrict__ wq,
                          const float* __restrict__ wp,
                          unsigned short* __restrict__ xb,
                          unsigned short* __restrict__ wqb,
                          unsigned short* __restrict__ wpb) {
  int i = blockIdx.x * blockDim.x + threadIdx.x;
  const float* in; unsigned short* out; int j = i;
  if (i < 2097152)        { in = x;  out = xb;  }
  else if (i < 2883584)   { in = wq; out = wqb; j = i - 2097152; }
  else                    { in = wp; out = wpb; j = i - 2883584; }
  float4 v = ((const float4*)in)[j];
  ushort4 o;
  o.x = f2bf(v.x); o.y = f2bf(v.y); o.z = f2bf(v.z); o.w = f2bf(v.w);
  ((ushort4*)out)[j] = o;
}

// ---------- QKV GEMM with fused RoPE + fp16 pack epilogue ----------
// Q pre-scaled by 0.125*log2(e) in fp32 -> flash softmax runs in exp2 domain.
__global__ __launch_bounds__(256) void k_gemm_qkv(
    const unsigned short* __restrict__ A, const unsigned short* __restrict__ Bm,
    unsigned short* __restrict__ Qf, unsigned short* __restrict__ Kf,
    unsigned short* __restrict__ Vb,
    const float* __restrict__ sin_t, const float* __restrict__ cos_t) {
  const int M_K = 1024;
  __shared__ unsigned short As[128 * 32];
  __shared__ unsigned short Bs[128 * 32];
  const int tid = threadIdx.x;
  const int lane = tid & 63;
  const int l15 = lane & 15, g = lane >> 4;
  const int wid = tid >> 6, wr = wid >> 1, wc = wid & 1;
  const long m0 = (long)blockIdx.y * 128, n0 = (long)blockIdx.x * 128;

  f32x4 acc[4][4] = {};

  for (int k0 = 0; k0 < M_K; k0 += 32) {
#pragma unroll
    for (int p = 0; p < 2; ++p) {
      int e = p * 256 + tid;
      int row = e >> 2, col = (e & 3) * 8;
      gload_lds16(A + (m0 + row) * M_K + k0 + col, (char*)As + e * 16);
      gload_lds16(Bm + (n0 + row) * M_K + k0 + col, (char*)Bs + e * 16);
    }
    __syncthreads();
    bf16x8 af[4], bfr[4];
#pragma unroll
    for (int i = 0; i < 4; ++i) {
      af[i]  = bc8(*(const s16x8*)&As[(wr * 64 + i * 16 + l15) * 32 + g * 8]);
      bfr[i] = bc8(*(const s16x8*)&Bs[(wc * 64 + i * 16 + l15) * 32 + g * 8]);
    }
#pragma unroll
    for (int mi = 0; mi < 4; ++mi)
#pragma unroll
      for (int ni = 0; ni < 4; ++ni)
        acc[mi][ni] = mfma_bf(af[mi], bfr[ni], acc[mi][ni]);
    __syncthreads();
  }

  const int colbase = (int)n0 + wc * 64;
  const int s  = colbase >> 10;           // 0=q 1=k 2=v
  const int h  = (colbase >> 6) & 15;
  const float QSC = 0.125f * 1.44269504089f;
#pragma unroll
  for (int mi = 0; mi < 4; ++mi)
#pragma unroll
    for (int r = 0; r < 4; ++r) {
      long m = m0 + wr * 64 + mi * 16 + g * 4 + r;
      int b = (int)(m >> 11), n = (int)(m & 2047);
      long slab = ((long)(b * 16 + h)) * 131072 + (long)n * 64;
      float v0 = acc[mi][0][r], v1 = acc[mi][1][r];
      float v2 = acc[mi][2][r], v3 = acc[mi][3][r];
      if (s == 2) {
        Vb[slab + l15]      = f2h(v0);
        Vb[slab + 16 + l15] = f2h(v1);
        Vb[slab + 32 + l15] = f2h(v2);
        Vb[slab + 48 + l15] = f2h(v3);
      } else {
        float o0 = v0, o1 = v1, o2 = v2, o3 = v3;
        if (n >= 4) {
          const float* cs = cos_t + (long)(n - 4) * 64;
          const float* sn = sin_t + (long)(n - 4) * 64;
          float c0 = cs[l15], c1 = cs[16 + l15], c2 = cs[32 + l15], c3 = cs[48 + l15];
          float s0 = sn[l15], s1 = sn[16 + l15], s2 = sn[32 + l15], s3 = sn[48 + l15];
          float t0 = o0, t1 = o1;
          o0 = o0 * c0 - o2 * s0;  o1 = o1 * c1 - o3 * s1;
          o2 = o2 * c2 + t0 * s2;  o3 = o3 * c3 + t1 * s3;
        }
        if (s == 0) { o0 *= QSC; o1 *= QSC; o2 *= QSC; o3 *= QSC; }
        unsigned short* H = (s == 0) ? Qf : Kf;
        H[slab + l15]      = f2h(o0);
        H[slab + 16 + l15] = f2h(o1);
        H[slab + 32 + l15] = f2h(o2);
        H[slab + 48 + l15] = f2h(o3);
      }
    }
}

// ---------- V transpose + key-permute ----------
// Vb [bh][2048 n][64 d] -> Vt [bh][64 d][2048 p]; within each 64-key tile,
// key kappa = 16*kt + 4*gg + r -> position p = ((kt&1)*4+gg)*8 + (kt>>1)*4 + r,
// so flash's PV B-operand comes straight from its pb registers.
__global__ __launch_bounds__(256) void k_vtrans(const unsigned short* __restrict__ Vb,
                                                unsigned short* __restrict__ Vt) {
  __shared__ unsigned short T[64 * 256];
  const int tid = threadIdx.x;
  const int bh = blockIdx.y;
  const int n0 = blockIdx.x * 256;
  const long slab = (long)bh * 131072;
#pragma unroll
  for (int it = 0; it < 8; ++it) {
    int u = it * 256 + tid;
    int key = u >> 3, dc = u & 7;
    s16x8 v = *(const s16x8*)&Vb[slab + (long)(n0 + key) * 64 + dc * 8];
#pragma unroll
    for (int i = 0; i < 8; ++i) {
      int d = dc * 8 + i;
      T[d * 256 + (key ^ (dc << 3))] = (unsigned short)v[i];
    }
  }
  __syncthreads();
#pragma unroll
  for (int it = 0; it < 8; ++it) {
    int w = it * 256 + tid;
    int d = w >> 5, uc = w & 31;           // uc: 16B-unit within 256-key row
    int tile = uc >> 3, unit = uc & 7;
    int hh = unit >> 2, gg = unit & 3;
    int ka = tile * 64 + hh * 16 + gg * 4; // keys ka..ka+3 and ka+32..ka+35
    int dc = d >> 3;
    s16x4 a = *(const s16x4*)&T[d * 256 + (ka ^ (dc << 3))];
    s16x4 b = *(const s16x4*)&T[d * 256 + ((ka + 32) ^ (dc << 3))];
    s16x8 v = {a[0], a[1], a[2], a[3], b[0], b[1], b[2], b[3]};
    *(s16x8*)&Vt[slab + (long)d * 2048 + n0 + uc * 8] = v;
  }
}

// ---------- generic bf16 GEMM (final projection), f32 out + bias ----------
__global__ __launch_bounds__(256) void k_gemm_proj(
    const unsigned short* __restrict__ A, const unsigned short* __restrict__ Bm,
    float* __restrict__ Cf, const float* __restrict__ bias, int M, int N, int K) {
  __shared__ unsigned short As[128 * 32];
  __shared__ unsigned short Bs[128 * 32];
  const int tid = threadIdx.x;
  const int lane = tid & 63;
  const int l15 = lane & 15, g = lane >> 4;
  const int wid = tid >> 6, wr = wid >> 1, wc = wid & 1;
  const long m0 = (long)blockIdx.y * 128, n0 = (long)blockIdx.x * 128;

  f32x4 acc[4][4] = {};

  for (int k0 = 0; k0 < K; k0 += 32) {
#pragma unroll
    for (int p = 0; p < 2; ++p) {
      int e = p * 256 + tid;
      int row = e >> 2, col = (e & 3) * 8;
      gload_lds16(A + (m0 + row) * K + k0 + col, (char*)As + e * 16);
      gload_lds16(Bm + (n0 + row) * K + k0 + col, (char*)Bs + e * 16);
    }
    __syncthreads();
    bf16x8 af[4], bfr[4];
#pragma unroll
    for (int i = 0; i < 4; ++i) {
      af[i]  = bc8(*(const s16x8*)&As[(wr * 64 + i * 16 + l15) * 32 + g * 8]);
      bfr[i] = bc8(*(const s16x8*)&Bs[(wc * 64 + i * 16 + l15) * 32 + g * 8]);
    }
#pragma unroll
    for (int mi = 0; mi < 4; ++mi)
#pragma unroll
      for (int ni = 0; ni < 4; ++ni)
        acc[mi][ni] = mfma_bf(af[mi], bfr[ni], acc[mi][ni]);
    __syncthreads();
  }

#pragma unroll
  for (int mi = 0; mi < 4; ++mi)
#pragma unroll
    for (int ni = 0; ni < 4; ++ni) {
      long col = n0 + wc * 64 + ni * 16 + l15;
#pragma unroll
      for (int r = 0; r < 4; ++r) {
        long row = m0 + wr * 64 + mi * 16 + g * 4 + r;
        Cf[row * N + col] = acc[mi][ni][r] + bias[col];
      }
    }
}

// ---------- MFMA flash attention (fp16, reg-direct PV B, K+V double-buffered) ----------
// Both K and V staged at loop TOP into buf cur^1; the end-of-tile __syncthreads
// (implicit vmcnt(0)+lgkmcnt(0) in EVERY wave + barrier) makes all waves' staged
// data visible before any wave enters tile t+1 -> no cross-wave LDS race.
// LDS: KS 16 KiB + VtS 16 KiB = 32 KiB.
__global__ __launch_bounds__(256) void k_flash(
    const unsigned short* __restrict__ Qf, const unsigned short* __restrict__ Kf,
    const unsigned short* __restrict__ Vt, unsigned short* __restrict__ o) {
  __shared__ unsigned short KS[2][64 * 64];
  __shared__ unsigned short VtS[2][64 * 64];
  const int tid = threadIdx.x;
  const int lane = tid & 63, wid = tid >> 6;
  const int l15 = lane & 15, g = lane >> 4;
  const int bh = blockIdx.y, b = bh >> 4, h = bh & 15;
  const int q0 = blockIdx.x * 64 + wid * 16;
  const long slab = (long)bh * 131072;

  const long qrow = slab + (long)(q0 + l15) * 64;
  f16x8 qf0 = hc8(*(const s16x8*)&Qf[qrow + g * 8]);
  f16x8 qf1 = hc8(*(const s16x8*)&Qf[qrow + 32 + g * 8]);

  f32x4 ovt[4] = {};
  float mrun = -1e30f, lrun = 0.f;

  auto stageK = [&](int buf, int t) {
    const int kv0 = t * 64;
#pragma unroll
    for (int p = 0; p < 2; ++p) {
      int u = p * 256 + tid;
      int row = u >> 3, cu = u & 7, c = cu ^ (row & 7);
      gload_lds16(Kf + slab + (long)(kv0 + row) * 64 + c * 8, (char*)&KS[buf][0] + u * 16);
    }
  };
  auto stageV = [&](int buf, int t) {
    const int kv0 = t * 64;
#pragma unroll
    for (int p = 0; p < 2; ++p) {
      int u = p * 256 + tid;
      int row = u >> 3, cu = u & 7, c = cu ^ (row & 7);
      gload_lds16(Vt + slab + (long)row * 2048 + kv0 + c * 8, (char*)&VtS[buf][0] + u * 16);
    }
  };

  stageK(0, 0);
  stageV(0, 0);
  __syncthreads();                 // tile 0 fully resident (all waves)

  for (int t = 0; t < 32; ++t) {
    const int cur = t & 1;
    if (t < 31) {                  // prefetch next tile; drains at end-of-tile barrier
      stageK(cur ^ 1, t + 1);
      stageV(cur ^ 1, t + 1);
    }

    // QK^T (fp16, exp2-domain, scale pre-folded into Q)
    f32x4 st[4];
    __builtin_amdgcn_s_setprio(1);
#pragma unroll
    for (int kt = 0; kt < 4; ++kt) {
      f32x4 sacc = {};
#pragma unroll
      for (int kk = 0; kk < 2; ++kk) {
        int row = kt * 16 + l15;
        int uu = row * 8 + ((kk * 4 + g) ^ (row & 7));
        f16x8 kf = hc8(*(const s16x8*)&KS[cur][uu * 8]);
        sacc = mfma_h(kf, kk ? qf1 : qf0, sacc);
      }
      st[kt] = sacc;
    }
    __builtin_amdgcn_s_setprio(0);

    // per-query tile max
    float m0a = fmaxf(fmaxf(st[0][0], st[0][1]), fmaxf(st[0][2], st[0][3]));
    float m1a = fmaxf(fmaxf(st[1][0], st[1][1]), fmaxf(st[1][2], st[1][3]));
    float m2a = fmaxf(fmaxf(st[2][0], st[2][1]), fmaxf(st[2][2], st[2][3]));
    float m3a = fmaxf(fmaxf(st[3][0], st[3][1]), fmaxf(st[3][2], st[3][3]));
    float tmax = fmaxf(fmaxf(m0a, m1a), fmaxf(m2a, m3a));
    tmax = fmaxf(tmax, __shfl_xor(tmax, 16));
    tmax = fmaxf(tmax, __shfl_xor(tmax, 32));

    // defer-max (THR=8 in log2 units: P bounded by 2^8, fp16-safe)
    if (!__all(tmax <= mrun + 8.f)) {
      float mnew = fmaxf(mrun, tmax);
      float corr = exp2i(mrun - mnew);
      lrun *= corr;
#pragma unroll
      for (int dt = 0; dt < 4; ++dt) ovt[dt] *= corr;
      mrun = mnew;
    }

    unsigned pb[4][2];
#pragma unroll
    for (int kt = 0; kt < 4; ++kt) {
      float p0 = exp2i(st[kt][0] - mrun);
      float p1 = exp2i(st[kt][1] - mrun);
      float p2 = exp2i(st[kt][2] - mrun);
      float p3 = exp2i(st[kt][3] - mrun);
      lrun += (p0 + p1) + (p2 + p3);
      pb[kt][0] = cvtpkh(p0, p1);
      pb[kt][1] = cvtpkh(p2, p3);
    }

    // PV: O^T[d][q] += V^T-frag x P-frag (B straight from regs; keys permuted in Vt)
    __builtin_amdgcn_s_setprio(1);
#pragma unroll
    for (int h2 = 0; h2 < 2; ++h2) {
      u32x4 braw = {pb[h2][0], pb[h2][1], pb[h2 + 2][0], pb[h2 + 2][1]};
      f16x8 pf = __builtin_bit_cast(f16x8, braw);
#pragma unroll
      for (int dt = 0; dt < 4; ++dt) {
        int d = dt * 16 + l15;
        int vv = d * 8 + ((h2 * 4 + g) ^ (d & 7));
        f16x8 vf = hc8(*(const s16x8*)&VtS[cur][vv * 8]);
        ovt[dt] = mfma_h(vf, pf, ovt[dt]);
      }
    }
    __builtin_amdgcn_s_setprio(0);
    __syncthreads();   // drains this wave's prefetch + barriers all waves
  }

  lrun += __shfl_xor(lrun, 16);
  lrun += __shfl_xor(lrun, 32);
  float rinv = 1.0f / lrun;
  long orow = ((long)(b * 2048 + q0 + l15)) * 1024 + h * 64;
#pragma unroll
  for (int dt = 0; dt < 4; ++dt) {
    ushort4 w4;
    w4.x = f2bf(ovt[dt][0] * rinv);
    w4.y = f2bf(ovt[dt][1] * rinv);
    w4.z = f2bf(ovt[dt][2] * rinv);
    w4.w = f2bf(ovt[dt][3] * rinv);
    *(ushort4*)&o[orow + dt * 16 + g * 4] = w4;
  }
}

// ---------- launcher ----------
extern "C" void kernel_launch(void* const* d_in, const int* in_sizes, int n_in,
                              void* d_out, int out_size, void* d_ws, size_t ws_size,
                              hipStream_t stream) {
  const float* x      = (const float*)d_in[0];
  const float* sin_t  = (const float*)d_in[1];
  const float* cos_t  = (const float*)d_in[2];
  const float* w_qkv  = (const float*)d_in[3];
  const float* w_proj = (const float*)d_in[4];
  const float* b_proj = (const float*)d_in[5];
  float* out = (float*)d_out;

  char* ws = (char*)d_ws;
  unsigned short* xb     = (unsigned short*)(ws);                 // 16 MiB
  unsigned short* wqkvb  = (unsigned short*)(ws + (16l << 20));   // 6 MiB
  unsigned short* wprojb = (unsigned short*)(ws + (22l << 20));   // 2 MiB
  unsigned short* Qf     = (unsigned short*)(ws + (24l << 20));   // 16 MiB
  unsigned short* Kf     = (unsigned short*)(ws + (40l << 20));   // 16 MiB
  unsigned short* Vb     = (unsigned short*)(ws + (56l << 20));   // 16 MiB
  unsigned short* Vt     = (unsigned short*)(ws + (72l << 20));   // 16 MiB
  unsigned short* ob     = xb;   // alias: xb dead after QKV GEMM

  k_cvt_all<<<12288, 256, 0, stream>>>(x, w_qkv, w_proj, xb, wqkvb, wprojb);

  k_gemm_qkv<<<dim3(24, 64), 256, 0, stream>>>(xb, wqkvb, Qf, Kf, Vb,
                                               sin_t, cos_t);
  k_vtrans<<<dim3(8, 64), 256, 0, stream>>>(Vb, Vt);
  k_flash<<<dim3(32, 64), 256, 0, stream>>>(Qf, Kf, Vt, ob);
  k_gemm_proj<<<dim3(8, 64), 256, 0, stream>>>(ob, wprojb, out, b_proj,
                                               8192, 1024, 1024);
}

// Round 13
// 261.667 us; speedup vs baseline: 1.4032x; 1.0187x over previous
//
#include <hip/hip_runtime.h>
#include <stdint.h>

// ---------- types ----------
typedef __bf16 bf16x8 __attribute__((ext_vector_type(8)));
typedef _Float16 f16x8 __attribute__((ext_vector_type(8)));
typedef float f32x4 __attribute__((ext_vector_type(4)));
typedef short s16x8 __attribute__((ext_vector_type(8)));
typedef short s16x4 __attribute__((ext_vector_type(4)));
typedef unsigned int u32x4 __attribute__((ext_vector_type(4)));

__device__ __forceinline__ unsigned short f2bf(float f) {
  unsigned u = __builtin_bit_cast(unsigned, f);
  u += 0x7fff + ((u >> 16) & 1);   // RNE
  return (unsigned short)(u >> 16);
}
__device__ __forceinline__ unsigned short f2h(float f) {
  return __builtin_bit_cast(unsigned short, (_Float16)f);
}
__device__ __forceinline__ float exp2i(float x) {    // v_exp_f32 = 2^x
  float r;
  asm("v_exp_f32 %0, %1" : "=v"(r) : "v"(x));
  return r;
}
__device__ __forceinline__ unsigned cvtpkh(float lo, float hi) {  // 2xf32 -> packed fp16
  auto r = __builtin_amdgcn_cvt_pkrtz(lo, hi);
  return __builtin_bit_cast(unsigned, r);
}

__device__ __forceinline__ void gload_lds16(const void* g, void* l) {
  __builtin_amdgcn_global_load_lds(
      (const __attribute__((address_space(1))) unsigned int*)g,
      (__attribute__((address_space(3))) unsigned int*)l, 16, 0, 0);
}

__device__ __forceinline__ f32x4 mfma_bf(bf16x8 a, bf16x8 b, f32x4 c) {
  return __builtin_amdgcn_mfma_f32_16x16x32_bf16(a, b, c, 0, 0, 0);
}
__device__ __forceinline__ f32x4 mfma_h(f16x8 a, f16x8 b, f32x4 c) {
  return __builtin_amdgcn_mfma_f32_16x16x32_f16(a, b, c, 0, 0, 0);
}
__device__ __forceinline__ bf16x8 bc8(s16x8 v) { return __builtin_bit_cast(bf16x8, v); }
__device__ __forceinline__ f16x8 hc8(s16x8 v) { return __builtin_bit_cast(f16x8, v); }

// ---------- fp32 -> bf16 convert (x, w_qkv, w_proj in one launch) ----------
__global__ void k_cvt_all(const float* __restrict__ x, const float* __restrict__ wq,
                          const float* __restrict__ wp,
                          unsigned short* __restrict__ xb,
                          unsigned short* __restrict__ wqb,
                          unsigned short* __restrict__ wpb) {
  int i = blockIdx.x * blockDim.x + threadIdx.x;
  const float* in; unsigned short* out; int j = i;
  if (i < 2097152)        { in = x;  out = xb;  }
  else if (i < 2883584)   { in = wq; out = wqb; j = i - 2097152; }
  else                    { in = wp; out = wpb; j = i - 2883584; }
  float4 v = ((const float4*)in)[j];
  ushort4 o;
  o.x = f2bf(v.x); o.y = f2bf(v.y); o.z = f2bf(v.z); o.w = f2bf(v.w);
  ((ushort4*)out)[j] = o;
}

// ---------- QKV GEMM with fused RoPE + fp16 pack epilogue ----------
// Q pre-scaled by 0.125*log2(e) in fp32 -> flash softmax runs in exp2 domain.
__global__ __launch_bounds__(256) void k_gemm_qkv(
    const unsigned short* __restrict__ A, const unsigned short* __restrict__ Bm,
    unsigned short* __restrict__ Qf, unsigned short* __restrict__ Kf,
    unsigned short* __restrict__ Vb,
    const float* __restrict__ sin_t, const float* __restrict__ cos_t) {
  const int M_K = 1024;
  __shared__ unsigned short As[128 * 32];
  __shared__ unsigned short Bs[128 * 32];
  const int tid = threadIdx.x;
  const int lane = tid & 63;
  const int l15 = lane & 15, g = lane >> 4;
  const int wid = tid >> 6, wr = wid >> 1, wc = wid & 1;
  const long m0 = (long)blockIdx.y * 128, n0 = (long)blockIdx.x * 128;

  f32x4 acc[4][4] = {};

  for (int k0 = 0; k0 < M_K; k0 += 32) {
#pragma unroll
    for (int p = 0; p < 2; ++p) {
      int e = p * 256 + tid;
      int row = e >> 2, col = (e & 3) * 8;
      gload_lds16(A + (m0 + row) * M_K + k0 + col, (char*)As + e * 16);
      gload_lds16(Bm + (n0 + row) * M_K + k0 + col, (char*)Bs + e * 16);
    }
    __syncthreads();
    bf16x8 af[4], bfr[4];
#pragma unroll
    for (int i = 0; i < 4; ++i) {
      af[i]  = bc8(*(const s16x8*)&As[(wr * 64 + i * 16 + l15) * 32 + g * 8]);
      bfr[i] = bc8(*(const s16x8*)&Bs[(wc * 64 + i * 16 + l15) * 32 + g * 8]);
    }
#pragma unroll
    for (int mi = 0; mi < 4; ++mi)
#pragma unroll
      for (int ni = 0; ni < 4; ++ni)
        acc[mi][ni] = mfma_bf(af[mi], bfr[ni], acc[mi][ni]);
    __syncthreads();
  }

  const int colbase = (int)n0 + wc * 64;
  const int s  = colbase >> 10;           // 0=q 1=k 2=v
  const int h  = (colbase >> 6) & 15;
  const float QSC = 0.125f * 1.44269504089f;
#pragma unroll
  for (int mi = 0; mi < 4; ++mi)
#pragma unroll
    for (int r = 0; r < 4; ++r) {
      long m = m0 + wr * 64 + mi * 16 + g * 4 + r;
      int b = (int)(m >> 11), n = (int)(m & 2047);
      long slab = ((long)(b * 16 + h)) * 131072 + (long)n * 64;
      float v0 = acc[mi][0][r], v1 = acc[mi][1][r];
      float v2 = acc[mi][2][r], v3 = acc[mi][3][r];
      if (s == 2) {
        Vb[slab + l15]      = f2h(v0);
        Vb[slab + 16 + l15] = f2h(v1);
        Vb[slab + 32 + l15] = f2h(v2);
        Vb[slab + 48 + l15] = f2h(v3);
      } else {
        float o0 = v0, o1 = v1, o2 = v2, o3 = v3;
        if (n >= 4) {
          const float* cs = cos_t + (long)(n - 4) * 64;
          const float* sn = sin_t + (long)(n - 4) * 64;
          float c0 = cs[l15], c1 = cs[16 + l15], c2 = cs[32 + l15], c3 = cs[48 + l15];
          float s0 = sn[l15], s1 = sn[16 + l15], s2 = sn[32 + l15], s3 = sn[48 + l15];
          float t0 = o0, t1 = o1;
          o0 = o0 * c0 - o2 * s0;  o1 = o1 * c1 - o3 * s1;
          o2 = o2 * c2 + t0 * s2;  o3 = o3 * c3 + t1 * s3;
        }
        if (s == 0) { o0 *= QSC; o1 *= QSC; o2 *= QSC; o3 *= QSC; }
        unsigned short* H = (s == 0) ? Qf : Kf;
        H[slab + l15]      = f2h(o0);
        H[slab + 16 + l15] = f2h(o1);
        H[slab + 32 + l15] = f2h(o2);
        H[slab + 48 + l15] = f2h(o3);
      }
    }
}

// ---------- V transpose + key-permute ----------
// Vb [bh][2048 n][64 d] -> Vt [bh][64 d][2048 p]; within each 64-key tile,
// key kappa = 16*kt + 4*gg + r -> position p = ((kt&1)*4+gg)*8 + (kt>>1)*4 + r,
// so flash's PV B-operand comes straight from its pb registers.
__global__ __launch_bounds__(256) void k_vtrans(const unsigned short* __restrict__ Vb,
                                                unsigned short* __restrict__ Vt) {
  __shared__ unsigned short T[64 * 256];
  const int tid = threadIdx.x;
  const int bh = blockIdx.y;
  const int n0 = blockIdx.x * 256;
  const long slab = (long)bh * 131072;
#pragma unroll
  for (int it = 0; it < 8; ++it) {
    int u = it * 256 + tid;
    int key = u >> 3, dc = u & 7;
    s16x8 v = *(const s16x8*)&Vb[slab + (long)(n0 + key) * 64 + dc * 8];
#pragma unroll
    for (int i = 0; i < 8; ++i) {
      int d = dc * 8 + i;
      T[d * 256 + (key ^ (dc << 3))] = (unsigned short)v[i];
    }
  }
  __syncthreads();
#pragma unroll
  for (int it = 0; it < 8; ++it) {
    int w = it * 256 + tid;
    int d = w >> 5, uc = w & 31;           // uc: 16B-unit within 256-key row
    int tile = uc >> 3, unit = uc & 7;
    int hh = unit >> 2, gg = unit & 3;
    int ka = tile * 64 + hh * 16 + gg * 4; // keys ka..ka+3 and ka+32..ka+35
    int dc = d >> 3;
    s16x4 a = *(const s16x4*)&T[d * 256 + (ka ^ (dc << 3))];
    s16x4 b = *(const s16x4*)&T[d * 256 + ((ka + 32) ^ (dc << 3))];
    s16x8 v = {a[0], a[1], a[2], a[3], b[0], b[1], b[2], b[3]};
    *(s16x8*)&Vt[slab + (long)d * 2048 + n0 + uc * 8] = v;
  }
}

// ---------- generic bf16 GEMM (final projection), f32 out + bias ----------
__global__ __launch_bounds__(256) void k_gemm_proj(
    const unsigned short* __restrict__ A, const unsigned short* __restrict__ Bm,
    float* __restrict__ Cf, const float* __restrict__ bias, int M, int N, int K) {
  __shared__ unsigned short As[128 * 32];
  __shared__ unsigned short Bs[128 * 32];
  const int tid = threadIdx.x;
  const int lane = tid & 63;
  const int l15 = lane & 15, g = lane >> 4;
  const int wid = tid >> 6, wr = wid >> 1, wc = wid & 1;
  const long m0 = (long)blockIdx.y * 128, n0 = (long)blockIdx.x * 128;

  f32x4 acc[4][4] = {};

  for (int k0 = 0; k0 < K; k0 += 32) {
#pragma unroll
    for (int p = 0; p < 2; ++p) {
      int e = p * 256 + tid;
      int row = e >> 2, col = (e & 3) * 8;
      gload_lds16(A + (m0 + row) * K + k0 + col, (char*)As + e * 16);
      gload_lds16(Bm + (n0 + row) * K + k0 + col, (char*)Bs + e * 16);
    }
    __syncthreads();
    bf16x8 af[4], bfr[4];
#pragma unroll
    for (int i = 0; i < 4; ++i) {
      af[i]  = bc8(*(const s16x8*)&As[(wr * 64 + i * 16 + l15) * 32 + g * 8]);
      bfr[i] = bc8(*(const s16x8*)&Bs[(wc * 64 + i * 16 + l15) * 32 + g * 8]);
    }
#pragma unroll
    for (int mi = 0; mi < 4; ++mi)
#pragma unroll
      for (int ni = 0; ni < 4; ++ni)
        acc[mi][ni] = mfma_bf(af[mi], bfr[ni], acc[mi][ni]);
    __syncthreads();
  }

#pragma unroll
  for (int mi = 0; mi < 4; ++mi)
#pragma unroll
    for (int ni = 0; ni < 4; ++ni) {
      long col = n0 + wc * 64 + ni * 16 + l15;
#pragma unroll
      for (int r = 0; r < 4; ++r) {
        long row = m0 + wr * 64 + mi * 16 + g * 4 + r;
        Cf[row * N + col] = acc[mi][ni][r] + bias[col];
      }
    }
}

// ---------- MFMA flash attention (fp16, 32 queries/wave, reg-direct PV B) ----------
// 4 waves x 32 q = 128 q/block; grid (16, 64) = 1024 blocks.
// Two 16-query groups (A,B) share every K/V LDS fragment -> per-query
// ds_reads, staging, and fixed costs halve vs 16q/wave. K+V double-buffered
// (32 KiB); end-of-tile __syncthreads (vmcnt(0) in all waves) = race-free.
__global__ __launch_bounds__(256) void k_flash(
    const unsigned short* __restrict__ Qf, const unsigned short* __restrict__ Kf,
    const unsigned short* __restrict__ Vt, unsigned short* __restrict__ o) {
  __shared__ unsigned short KS[2][64 * 64];
  __shared__ unsigned short VtS[2][64 * 64];
  const int tid = threadIdx.x;
  const int lane = tid & 63, wid = tid >> 6;
  const int l15 = lane & 15, g = lane >> 4;
  const int bh = blockIdx.y, b = bh >> 4, h = bh & 15;
  const int q0 = blockIdx.x * 128 + wid * 32;
  const long slab = (long)bh * 131072;

  const long qrowA = slab + (long)(q0 + l15) * 64;
  const long qrowB = slab + (long)(q0 + 16 + l15) * 64;
  f16x8 qa0 = hc8(*(const s16x8*)&Qf[qrowA + g * 8]);
  f16x8 qa1 = hc8(*(const s16x8*)&Qf[qrowA + 32 + g * 8]);
  f16x8 qb0 = hc8(*(const s16x8*)&Qf[qrowB + g * 8]);
  f16x8 qb1 = hc8(*(const s16x8*)&Qf[qrowB + 32 + g * 8]);

  f32x4 ova[4] = {}, ovb[4] = {};
  float mrunA = -1e30f, lrunA = 0.f;
  float mrunB = -1e30f, lrunB = 0.f;

  // strength-reduced staging pointers (advance by constants each tile)
  const int srow = tid >> 3, scu = tid & 7, sc = scu ^ (srow & 7);
  const unsigned short* kSrc0 = Kf + slab + (long)srow * 64 + sc * 8;
  const unsigned short* kSrc1 = kSrc0 + 2048;          // rows 32..63
  const unsigned short* vSrc0 = Vt + slab + (long)srow * 2048 + sc * 8;
  const unsigned short* vSrc1 = vSrc0 + 32 * 2048;     // dims 32..63

  auto stage = [&](int buf) {
    gload_lds16(kSrc0, (char*)&KS[buf][0] + tid * 16);
    gload_lds16(kSrc1, (char*)&KS[buf][0] + (256 + tid) * 16);
    gload_lds16(vSrc0, (char*)&VtS[buf][0] + tid * 16);
    gload_lds16(vSrc1, (char*)&VtS[buf][0] + (256 + tid) * 16);
    kSrc0 += 4096; kSrc1 += 4096;   // next 64-key tile (64*64 elems)
    vSrc0 += 64;   vSrc1 += 64;     // next 64 keys along the 2048-key rows
  };

  stage(0);
  __syncthreads();                  // tile 0 fully resident (all waves)

  for (int t = 0; t < 32; ++t) {
    const int cur = t & 1;
    if (t < 31) stage(cur ^ 1);     // prefetch; drains at end-of-tile barrier

    // QK^T: each K fragment feeds BOTH query groups
    f32x4 sa[4], sb[4];
    __builtin_amdgcn_s_setprio(1);
#pragma unroll
    for (int kt = 0; kt < 4; ++kt) {
      f32x4 xa = {}, xb = {};
#pragma unroll
      for (int kk = 0; kk < 2; ++kk) {
        int row = kt * 16 + l15;
        int uu = row * 8 + ((kk * 4 + g) ^ (row & 7));
        f16x8 kf = hc8(*(const s16x8*)&KS[cur][uu * 8]);
        xa = mfma_h(kf, kk ? qa1 : qa0, xa);
        xb = mfma_h(kf, kk ? qb1 : qb0, xb);
      }
      sa[kt] = xa; sb[kt] = xb;
    }
    __builtin_amdgcn_s_setprio(0);

    // per-query tile max (both groups)
    float ta = fmaxf(fmaxf(fmaxf(sa[0][0], sa[0][1]), fmaxf(sa[0][2], sa[0][3])),
                     fmaxf(fmaxf(sa[1][0], sa[1][1]), fmaxf(sa[1][2], sa[1][3])));
    ta = fmaxf(ta, fmaxf(fmaxf(fmaxf(sa[2][0], sa[2][1]), fmaxf(sa[2][2], sa[2][3])),
                         fmaxf(fmaxf(sa[3][0], sa[3][1]), fmaxf(sa[3][2], sa[3][3]))));
    float tb = fmaxf(fmaxf(fmaxf(sb[0][0], sb[0][1]), fmaxf(sb[0][2], sb[0][3])),
                     fmaxf(fmaxf(sb[1][0], sb[1][1]), fmaxf(sb[1][2], sb[1][3])));
    tb = fmaxf(tb, fmaxf(fmaxf(fmaxf(sb[2][0], sb[2][1]), fmaxf(sb[2][2], sb[2][3])),
                         fmaxf(fmaxf(sb[3][0], sb[3][1]), fmaxf(sb[3][2], sb[3][3]))));
    ta = fmaxf(ta, __shfl_xor(ta, 16)); ta = fmaxf(ta, __shfl_xor(ta, 32));
    tb = fmaxf(tb, __shfl_xor(tb, 16)); tb = fmaxf(tb, __shfl_xor(tb, 32));

    // defer-max (THR=8 in log2 units; P bounded by 2^8, fp16-safe)
    if (!__all(ta <= mrunA + 8.f && tb <= mrunB + 8.f)) {
      float mA = fmaxf(mrunA, ta), mB = fmaxf(mrunB, tb);
      float cA = exp2i(mrunA - mA), cB = exp2i(mrunB - mB);
      lrunA *= cA; lrunB *= cB;
#pragma unroll
      for (int dt = 0; dt < 4; ++dt) { ova[dt] *= cA; ovb[dt] *= cB; }
      mrunA = mA; mrunB = mB;
    }

    unsigned pa[4][2], pbv[4][2];
#pragma unroll
    for (int kt = 0; kt < 4; ++kt) {
      float a0 = exp2i(sa[kt][0] - mrunA), a1 = exp2i(sa[kt][1] - mrunA);
      float a2 = exp2i(sa[kt][2] - mrunA), a3 = exp2i(sa[kt][3] - mrunA);
      float b0 = exp2i(sb[kt][0] - mrunB), b1 = exp2i(sb[kt][1] - mrunB);
      float b2 = exp2i(sb[kt][2] - mrunB), b3 = exp2i(sb[kt][3] - mrunB);
      lrunA += (a0 + a1) + (a2 + a3);
      lrunB += (b0 + b1) + (b2 + b3);
      pa[kt][0]  = cvtpkh(a0, a1); pa[kt][1]  = cvtpkh(a2, a3);
      pbv[kt][0] = cvtpkh(b0, b1); pbv[kt][1] = cvtpkh(b2, b3);
    }

    // PV: each V fragment feeds BOTH query groups
    __builtin_amdgcn_s_setprio(1);
#pragma unroll
    for (int h2 = 0; h2 < 2; ++h2) {
      u32x4 brawA = {pa[h2][0], pa[h2][1], pa[h2 + 2][0], pa[h2 + 2][1]};
      u32x4 brawB = {pbv[h2][0], pbv[h2][1], pbv[h2 + 2][0], pbv[h2 + 2][1]};
      f16x8 pfA = __builtin_bit_cast(f16x8, brawA);
      f16x8 pfB = __builtin_bit_cast(f16x8, brawB);
#pragma unroll
      for (int dt = 0; dt < 4; ++dt) {
        int d = dt * 16 + l15;
        int vv = d * 8 + ((h2 * 4 + g) ^ (d & 7));
        f16x8 vf = hc8(*(const s16x8*)&VtS[cur][vv * 8]);
        ova[dt] = mfma_h(vf, pfA, ova[dt]);
        ovb[dt] = mfma_h(vf, pfB, ovb[dt]);
      }
    }
    __builtin_amdgcn_s_setprio(0);
    __syncthreads();   // drains this wave's prefetch + barriers all waves
  }

  lrunA += __shfl_xor(lrunA, 16); lrunA += __shfl_xor(lrunA, 32);
  lrunB += __shfl_xor(lrunB, 16); lrunB += __shfl_xor(lrunB, 32);
  float rA = 1.0f / lrunA, rB = 1.0f / lrunB;
  long orowA = ((long)(b * 2048 + q0 + l15)) * 1024 + h * 64;
  long orowB = ((long)(b * 2048 + q0 + 16 + l15)) * 1024 + h * 64;
#pragma unroll
  for (int dt = 0; dt < 4; ++dt) {
    ushort4 wa, wb;
    wa.x = f2bf(ova[dt][0] * rA); wa.y = f2bf(ova[dt][1] * rA);
    wa.z = f2bf(ova[dt][2] * rA); wa.w = f2bf(ova[dt][3] * rA);
    wb.x = f2bf(ovb[dt][0] * rB); wb.y = f2bf(ovb[dt][1] * rB);
    wb.z = f2bf(ovb[dt][2] * rB); wb.w = f2bf(ovb[dt][3] * rB);
    *(ushort4*)&o[orowA + dt * 16 + g * 4] = wa;
    *(ushort4*)&o[orowB + dt * 16 + g * 4] = wb;
  }
}

// ---------- launcher ----------
extern "C" void kernel_launch(void* const* d_in, const int* in_sizes, int n_in,
                              void* d_out, int out_size, void* d_ws, size_t ws_size,
                              hipStream_t stream) {
  const float* x      = (const float*)d_in[0];
  const float* sin_t  = (const float*)d_in[1];
  const float* cos_t  = (const float*)d_in[2];
  const float* w_qkv  = (const float*)d_in[3];
  const float* w_proj = (const float*)d_in[4];
  const float* b_proj = (const float*)d_in[5];
  float* out = (float*)d_out;

  char* ws = (char*)d_ws;
  unsigned short* xb     = (unsigned short*)(ws);                 // 16 MiB
  unsigned short* wqkvb  = (unsigned short*)(ws + (16l << 20));   // 6 MiB
  unsigned short* wprojb = (unsigned short*)(ws + (22l << 20));   // 2 MiB
  unsigned short* Qf     = (unsigned short*)(ws + (24l << 20));   // 16 MiB
  unsigned short* Kf     = (unsigned short*)(ws + (40l << 20));   // 16 MiB
  unsigned short* Vb     = (unsigned short*)(ws + (56l << 20));   // 16 MiB
  unsigned short* Vt     = (unsigned short*)(ws + (72l << 20));   // 16 MiB
  unsigned short* ob     = xb;   // alias: xb dead after QKV GEMM

  k_cvt_all<<<12288, 256, 0, stream>>>(x, w_qkv, w_proj, xb, wqkvb, wprojb);

  k_gemm_qkv<<<dim3(24, 64), 256, 0, stream>>>(xb, wqkvb, Qf, Kf, Vb,
                                               sin_t, cos_t);
  k_vtrans<<<dim3(8, 64), 256, 0, stream>>>(Vb, Vt);
  k_flash<<<dim3(16, 64), 256, 0, stream>>>(Qf, Kf, Vt, ob);
  k_gemm_proj<<<dim3(8, 64), 256, 0, stream>>>(ob, wprojb, out, b_proj,
                                               8192, 1024, 1024);
}

// Round 14
// 259.093 us; speedup vs baseline: 1.4171x; 1.0099x over previous
//
#include <hip/hip_runtime.h>
#include <stdint.h>

// ---------- types ----------
typedef __bf16 bf16x8 __attribute__((ext_vector_type(8)));
typedef _Float16 f16x8 __attribute__((ext_vector_type(8)));
typedef float f32x4 __attribute__((ext_vector_type(4)));
typedef short s16x8 __attribute__((ext_vector_type(8)));
typedef short s16x4 __attribute__((ext_vector_type(4)));
typedef unsigned int u32x4 __attribute__((ext_vector_type(4)));

__device__ __forceinline__ unsigned short f2bf(float f) {
  unsigned u = __builtin_bit_cast(unsigned, f);
  u += 0x7fff + ((u >> 16) & 1);   // RNE
  return (unsigned short)(u >> 16);
}
__device__ __forceinline__ unsigned short f2h(float f) {
  return __builtin_bit_cast(unsigned short, (_Float16)f);
}
__device__ __forceinline__ float exp2i(float x) {    // v_exp_f32 = 2^x
  float r;
  asm("v_exp_f32 %0, %1" : "=v"(r) : "v"(x));
  return r;
}
__device__ __forceinline__ unsigned cvtpkh(float lo, float hi) {  // 2xf32 -> packed fp16
  auto r = __builtin_amdgcn_cvt_pkrtz(lo, hi);
  return __builtin_bit_cast(unsigned, r);
}

__device__ __forceinline__ void gload_lds16(const void* g, void* l) {
  __builtin_amdgcn_global_load_lds(
      (const __attribute__((address_space(1))) unsigned int*)g,
      (__attribute__((address_space(3))) unsigned int*)l, 16, 0, 0);
}

__device__ __forceinline__ f32x4 mfma_bf(bf16x8 a, bf16x8 b, f32x4 c) {
  return __builtin_amdgcn_mfma_f32_16x16x32_bf16(a, b, c, 0, 0, 0);
}
__device__ __forceinline__ f32x4 mfma_h(f16x8 a, f16x8 b, f32x4 c) {
  return __builtin_amdgcn_mfma_f32_16x16x32_f16(a, b, c, 0, 0, 0);
}
__device__ __forceinline__ bf16x8 bc8(s16x8 v) { return __builtin_bit_cast(bf16x8, v); }
__device__ __forceinline__ f16x8 hc8(s16x8 v) { return __builtin_bit_cast(f16x8, v); }

// ---------- fp32 -> bf16 convert (x, w_qkv, w_proj in one launch) ----------
__global__ void k_cvt_all(const float* __restrict__ x, const float* __restrict__ wq,
                          const float* __restrict__ wp,
                          unsigned short* __restrict__ xb,
                          unsigned short* __restrict__ wqb,
                          unsigned short* __restrict__ wpb) {
  int i = blockIdx.x * blockDim.x + threadIdx.x;
  const float* in; unsigned short* out; int j = i;
  if (i < 2097152)        { in = x;  out = xb;  }
  else if (i < 2883584)   { in = wq; out = wqb; j = i - 2097152; }
  else                    { in = wp; out = wpb; j = i - 2883584; }
  float4 v = ((const float4*)in)[j];
  ushort4 o;
  o.x = f2bf(v.x); o.y = f2bf(v.y); o.z = f2bf(v.z); o.w = f2bf(v.w);
  ((ushort4*)out)[j] = o;
}

// ---------- QKV GEMM with fused RoPE + fp16 pack epilogue ----------
// Q pre-scaled by 0.125*log2(e) in fp32 -> flash softmax runs in exp2 domain.
__global__ __launch_bounds__(256) void k_gemm_qkv(
    const unsigned short* __restrict__ A, const unsigned short* __restrict__ Bm,
    unsigned short* __restrict__ Qf, unsigned short* __restrict__ Kf,
    unsigned short* __restrict__ Vb,
    const float* __restrict__ sin_t, const float* __restrict__ cos_t) {
  const int M_K = 1024;
  __shared__ unsigned short As[128 * 32];
  __shared__ unsigned short Bs[128 * 32];
  const int tid = threadIdx.x;
  const int lane = tid & 63;
  const int l15 = lane & 15, g = lane >> 4;
  const int wid = tid >> 6, wr = wid >> 1, wc = wid & 1;
  const long m0 = (long)blockIdx.y * 128, n0 = (long)blockIdx.x * 128;

  f32x4 acc[4][4] = {};

  for (int k0 = 0; k0 < M_K; k0 += 32) {
#pragma unroll
    for (int p = 0; p < 2; ++p) {
      int e = p * 256 + tid;
      int row = e >> 2, col = (e & 3) * 8;
      gload_lds16(A + (m0 + row) * M_K + k0 + col, (char*)As + e * 16);
      gload_lds16(Bm + (n0 + row) * M_K + k0 + col, (char*)Bs + e * 16);
    }
    __syncthreads();
    bf16x8 af[4], bfr[4];
#pragma unroll
    for (int i = 0; i < 4; ++i) {
      af[i]  = bc8(*(const s16x8*)&As[(wr * 64 + i * 16 + l15) * 32 + g * 8]);
      bfr[i] = bc8(*(const s16x8*)&Bs[(wc * 64 + i * 16 + l15) * 32 + g * 8]);
    }
#pragma unroll
    for (int mi = 0; mi < 4; ++mi)
#pragma unroll
      for (int ni = 0; ni < 4; ++ni)
        acc[mi][ni] = mfma_bf(af[mi], bfr[ni], acc[mi][ni]);
    __syncthreads();
  }

  const int colbase = (int)n0 + wc * 64;
  const int s  = colbase >> 10;           // 0=q 1=k 2=v
  const int h  = (colbase >> 6) & 15;
  const float QSC = 0.125f * 1.44269504089f;
#pragma unroll
  for (int mi = 0; mi < 4; ++mi)
#pragma unroll
    for (int r = 0; r < 4; ++r) {
      long m = m0 + wr * 64 + mi * 16 + g * 4 + r;
      int b = (int)(m >> 11), n = (int)(m & 2047);
      long slab = ((long)(b * 16 + h)) * 131072 + (long)n * 64;
      float v0 = acc[mi][0][r], v1 = acc[mi][1][r];
      float v2 = acc[mi][2][r], v3 = acc[mi][3][r];
      if (s == 2) {
        Vb[slab + l15]      = f2h(v0);
        Vb[slab + 16 + l15] = f2h(v1);
        Vb[slab + 32 + l15] = f2h(v2);
        Vb[slab + 48 + l15] = f2h(v3);
      } else {
        float o0 = v0, o1 = v1, o2 = v2, o3 = v3;
        if (n >= 4) {
          const float* cs = cos_t + (long)(n - 4) * 64;
          const float* sn = sin_t + (long)(n - 4) * 64;
          float c0 = cs[l15], c1 = cs[16 + l15], c2 = cs[32 + l15], c3 = cs[48 + l15];
          float s0 = sn[l15], s1 = sn[16 + l15], s2 = sn[32 + l15], s3 = sn[48 + l15];
          float t0 = o0, t1 = o1;
          o0 = o0 * c0 - o2 * s0;  o1 = o1 * c1 - o3 * s1;
          o2 = o2 * c2 + t0 * s2;  o3 = o3 * c3 + t1 * s3;
        }
        if (s == 0) { o0 *= QSC; o1 *= QSC; o2 *= QSC; o3 *= QSC; }
        unsigned short* H = (s == 0) ? Qf : Kf;
        H[slab + l15]      = f2h(o0);
        H[slab + 16 + l15] = f2h(o1);
        H[slab + 32 + l15] = f2h(o2);
        H[slab + 48 + l15] = f2h(o3);
      }
    }
}

// ---------- V transpose + key-permute ----------
// Vb [bh][2048 n][64 d] -> Vt [bh][64 d][2048 p]; within each 64-key tile,
// key kappa = 16*kt + 4*gg + r -> position p = ((kt&1)*4+gg)*8 + (kt>>1)*4 + r,
// so flash's PV B-operand comes straight from its pb registers.
__global__ __launch_bounds__(256) void k_vtrans(const unsigned short* __restrict__ Vb,
                                                unsigned short* __restrict__ Vt) {
  __shared__ unsigned short T[64 * 256];
  const int tid = threadIdx.x;
  const int bh = blockIdx.y;
  const int n0 = blockIdx.x * 256;
  const long slab = (long)bh * 131072;
#pragma unroll
  for (int it = 0; it < 8; ++it) {
    int u = it * 256 + tid;
    int key = u >> 3, dc = u & 7;
    s16x8 v = *(const s16x8*)&Vb[slab + (long)(n0 + key) * 64 + dc * 8];
#pragma unroll
    for (int i = 0; i < 8; ++i) {
      int d = dc * 8 + i;
      T[d * 256 + (key ^ (dc << 3))] = (unsigned short)v[i];
    }
  }
  __syncthreads();
#pragma unroll
  for (int it = 0; it < 8; ++it) {
    int w = it * 256 + tid;
    int d = w >> 5, uc = w & 31;           // uc: 16B-unit within 256-key row
    int tile = uc >> 3, unit = uc & 7;
    int hh = unit >> 2, gg = unit & 3;
    int ka = tile * 64 + hh * 16 + gg * 4; // keys ka..ka+3 and ka+32..ka+35
    int dc = d >> 3;
    s16x4 a = *(const s16x4*)&T[d * 256 + (ka ^ (dc << 3))];
    s16x4 b = *(const s16x4*)&T[d * 256 + ((ka + 32) ^ (dc << 3))];
    s16x8 v = {a[0], a[1], a[2], a[3], b[0], b[1], b[2], b[3]};
    *(s16x8*)&Vt[slab + (long)d * 2048 + n0 + uc * 8] = v;
  }
}

// ---------- generic bf16 GEMM (final projection), f32 out + bias ----------
__global__ __launch_bounds__(256) void k_gemm_proj(
    const unsigned short* __restrict__ A, const unsigned short* __restrict__ Bm,
    float* __restrict__ Cf, const float* __restrict__ bias, int M, int N, int K) {
  __shared__ unsigned short As[128 * 32];
  __shared__ unsigned short Bs[128 * 32];
  const int tid = threadIdx.x;
  const int lane = tid & 63;
  const int l15 = lane & 15, g = lane >> 4;
  const int wid = tid >> 6, wr = wid >> 1, wc = wid & 1;
  const long m0 = (long)blockIdx.y * 128, n0 = (long)blockIdx.x * 128;

  f32x4 acc[4][4] = {};

  for (int k0 = 0; k0 < K; k0 += 32) {
#pragma unroll
    for (int p = 0; p < 2; ++p) {
      int e = p * 256 + tid;
      int row = e >> 2, col = (e & 3) * 8;
      gload_lds16(A + (m0 + row) * K + k0 + col, (char*)As + e * 16);
      gload_lds16(Bm + (n0 + row) * K + k0 + col, (char*)Bs + e * 16);
    }
    __syncthreads();
    bf16x8 af[4], bfr[4];
#pragma unroll
    for (int i = 0; i < 4; ++i) {
      af[i]  = bc8(*(const s16x8*)&As[(wr * 64 + i * 16 + l15) * 32 + g * 8]);
      bfr[i] = bc8(*(const s16x8*)&Bs[(wc * 64 + i * 16 + l15) * 32 + g * 8]);
    }
#pragma unroll
    for (int mi = 0; mi < 4; ++mi)
#pragma unroll
      for (int ni = 0; ni < 4; ++ni)
        acc[mi][ni] = mfma_bf(af[mi], bfr[ni], acc[mi][ni]);
    __syncthreads();
  }

#pragma unroll
  for (int mi = 0; mi < 4; ++mi)
#pragma unroll
    for (int ni = 0; ni < 4; ++ni) {
      long col = n0 + wc * 64 + ni * 16 + l15;
#pragma unroll
      for (int r = 0; r < 4; ++r) {
        long row = m0 + wr * 64 + mi * 16 + g * 4 + r;
        Cf[row * N + col] = acc[mi][ni][r] + bias[col];
      }
    }
}

// ---------- MFMA flash attention (fp16, 32 q/wave, XCD-local bh swizzle) ----------
// 1-D grid of 1024 blocks; j = s*8 + c with c = bh&7 (XCD class), s = (bh>>3)*16 + qt.
// Assuming round-robin block->XCD dispatch (j%8), each XCD serves only 8 distinct
// bh-slabs, and its ~64 resident blocks cover ~4 bh x 16 qtiles = 2 MB of K/V
// -> L2-resident staging, no thrash (was: 64 bh spread everywhere, 139 MB FETCH).
__global__ __launch_bounds__(256) void k_flash(
    const unsigned short* __restrict__ Qf, const unsigned short* __restrict__ Kf,
    const unsigned short* __restrict__ Vt, unsigned short* __restrict__ o) {
  __shared__ unsigned short KS[2][64 * 64];
  __shared__ unsigned short VtS[2][64 * 64];
  const int tid = threadIdx.x;
  const int lane = tid & 63, wid = tid >> 6;
  const int l15 = lane & 15, g = lane >> 4;
  const int j = blockIdx.x;
  const int c = j & 7, s = j >> 3;
  const int bh = ((s >> 4) << 3) | c;      // bijective: bh in [0,64)
  const int qt = s & 15;
  const int b = bh >> 4, h = bh & 15;
  const int q0 = qt * 128 + wid * 32;
  const long slab = (long)bh * 131072;

  const long qrowA = slab + (long)(q0 + l15) * 64;
  const long qrowB = slab + (long)(q0 + 16 + l15) * 64;
  f16x8 qa0 = hc8(*(const s16x8*)&Qf[qrowA + g * 8]);
  f16x8 qa1 = hc8(*(const s16x8*)&Qf[qrowA + 32 + g * 8]);
  f16x8 qb0 = hc8(*(const s16x8*)&Qf[qrowB + g * 8]);
  f16x8 qb1 = hc8(*(const s16x8*)&Qf[qrowB + 32 + g * 8]);

  f32x4 ova[4] = {}, ovb[4] = {};
  float mrunA = -1e30f, lrunA = 0.f;
  float mrunB = -1e30f, lrunB = 0.f;

  // strength-reduced staging pointers (advance by constants each tile)
  const int srow = tid >> 3, scu = tid & 7, sc = scu ^ (srow & 7);
  const unsigned short* kSrc0 = Kf + slab + (long)srow * 64 + sc * 8;
  const unsigned short* kSrc1 = kSrc0 + 2048;          // rows 32..63
  const unsigned short* vSrc0 = Vt + slab + (long)srow * 2048 + sc * 8;
  const unsigned short* vSrc1 = vSrc0 + 32 * 2048;     // dims 32..63

  auto stage = [&](int buf) {
    gload_lds16(kSrc0, (char*)&KS[buf][0] + tid * 16);
    gload_lds16(kSrc1, (char*)&KS[buf][0] + (256 + tid) * 16);
    gload_lds16(vSrc0, (char*)&VtS[buf][0] + tid * 16);
    gload_lds16(vSrc1, (char*)&VtS[buf][0] + (256 + tid) * 16);
    kSrc0 += 4096; kSrc1 += 4096;   // next 64-key tile (64*64 elems)
    vSrc0 += 64;   vSrc1 += 64;     // next 64 keys along the 2048-key rows
  };

  stage(0);
  __syncthreads();                  // tile 0 fully resident (all waves)

  for (int t = 0; t < 32; ++t) {
    const int cur = t & 1;
    if (t < 31) stage(cur ^ 1);     // prefetch; drains at end-of-tile barrier

    // QK^T: each K fragment feeds BOTH query groups
    f32x4 sa[4], sb[4];
    __builtin_amdgcn_s_setprio(1);
#pragma unroll
    for (int kt = 0; kt < 4; ++kt) {
      f32x4 xa = {}, xb = {};
#pragma unroll
      for (int kk = 0; kk < 2; ++kk) {
        int row = kt * 16 + l15;
        int uu = row * 8 + ((kk * 4 + g) ^ (row & 7));
        f16x8 kf = hc8(*(const s16x8*)&KS[cur][uu * 8]);
        xa = mfma_h(kf, kk ? qa1 : qa0, xa);
        xb = mfma_h(kf, kk ? qb1 : qb0, xb);
      }
      sa[kt] = xa; sb[kt] = xb;
    }
    __builtin_amdgcn_s_setprio(0);

    // per-query tile max (both groups)
    float ta = fmaxf(fmaxf(fmaxf(sa[0][0], sa[0][1]), fmaxf(sa[0][2], sa[0][3])),
                     fmaxf(fmaxf(sa[1][0], sa[1][1]), fmaxf(sa[1][2], sa[1][3])));
    ta = fmaxf(ta, fmaxf(fmaxf(fmaxf(sa[2][0], sa[2][1]), fmaxf(sa[2][2], sa[2][3])),
                         fmaxf(fmaxf(sa[3][0], sa[3][1]), fmaxf(sa[3][2], sa[3][3]))));
    float tb = fmaxf(fmaxf(fmaxf(sb[0][0], sb[0][1]), fmaxf(sb[0][2], sb[0][3])),
                     fmaxf(fmaxf(sb[1][0], sb[1][1]), fmaxf(sb[1][2], sb[1][3])));
    tb = fmaxf(tb, fmaxf(fmaxf(fmaxf(sb[2][0], sb[2][1]), fmaxf(sb[2][2], sb[2][3])),
                         fmaxf(fmaxf(sb[3][0], sb[3][1]), fmaxf(sb[3][2], sb[3][3]))));
    ta = fmaxf(ta, __shfl_xor(ta, 16)); ta = fmaxf(ta, __shfl_xor(ta, 32));
    tb = fmaxf(tb, __shfl_xor(tb, 16)); tb = fmaxf(tb, __shfl_xor(tb, 32));

    // defer-max (THR=8 in log2 units; P bounded by 2^8, fp16-safe)
    if (!__all(ta <= mrunA + 8.f && tb <= mrunB + 8.f)) {
      float mA = fmaxf(mrunA, ta), mB = fmaxf(mrunB, tb);
      float cA = exp2i(mrunA - mA), cB = exp2i(mrunB - mB);
      lrunA *= cA; lrunB *= cB;
#pragma unroll
      for (int dt = 0; dt < 4; ++dt) { ova[dt] *= cA; ovb[dt] *= cB; }
      mrunA = mA; mrunB = mB;
    }

    unsigned pa[4][2], pbv[4][2];
#pragma unroll
    for (int kt = 0; kt < 4; ++kt) {
      float a0 = exp2i(sa[kt][0] - mrunA), a1 = exp2i(sa[kt][1] - mrunA);
      float a2 = exp2i(sa[kt][2] - mrunA), a3 = exp2i(sa[kt][3] - mrunA);
      float b0 = exp2i(sb[kt][0] - mrunB), b1 = exp2i(sb[kt][1] - mrunB);
      float b2 = exp2i(sb[kt][2] - mrunB), b3 = exp2i(sb[kt][3] - mrunB);
      lrunA += (a0 + a1) + (a2 + a3);
      lrunB += (b0 + b1) + (b2 + b3);
      pa[kt][0]  = cvtpkh(a0, a1); pa[kt][1]  = cvtpkh(a2, a3);
      pbv[kt][0] = cvtpkh(b0, b1); pbv[kt][1] = cvtpkh(b2, b3);
    }

    // PV: each V fragment feeds BOTH query groups
    __builtin_amdgcn_s_setprio(1);
#pragma unroll
    for (int h2 = 0; h2 < 2; ++h2) {
      u32x4 brawA = {pa[h2][0], pa[h2][1], pa[h2 + 2][0], pa[h2 + 2][1]};
      u32x4 brawB = {pbv[h2][0], pbv[h2][1], pbv[h2 + 2][0], pbv[h2 + 2][1]};
      f16x8 pfA = __builtin_bit_cast(f16x8, brawA);
      f16x8 pfB = __builtin_bit_cast(f16x8, brawB);
#pragma unroll
      for (int dt = 0; dt < 4; ++dt) {
        int d = dt * 16 + l15;
        int vv = d * 8 + ((h2 * 4 + g) ^ (d & 7));
        f16x8 vf = hc8(*(const s16x8*)&VtS[cur][vv * 8]);
        ova[dt] = mfma_h(vf, pfA, ova[dt]);
        ovb[dt] = mfma_h(vf, pfB, ovb[dt]);
      }
    }
    __builtin_amdgcn_s_setprio(0);
    __syncthreads();   // drains this wave's prefetch + barriers all waves
  }

  lrunA += __shfl_xor(lrunA, 16); lrunA += __shfl_xor(lrunA, 32);
  lrunB += __shfl_xor(lrunB, 16); lrunB += __shfl_xor(lrunB, 32);
  float rA = 1.0f / lrunA, rB = 1.0f / lrunB;
  long orowA = ((long)(b * 2048 + q0 + l15)) * 1024 + h * 64;
  long orowB = ((long)(b * 2048 + q0 + 16 + l15)) * 1024 + h * 64;
#pragma unroll
  for (int dt = 0; dt < 4; ++dt) {
    ushort4 wa, wb;
    wa.x = f2bf(ova[dt][0] * rA); wa.y = f2bf(ova[dt][1] * rA);
    wa.z = f2bf(ova[dt][2] * rA); wa.w = f2bf(ova[dt][3] * rA);
    wb.x = f2bf(ovb[dt][0] * rB); wb.y = f2bf(ovb[dt][1] * rB);
    wb.z = f2bf(ovb[dt][2] * rB); wb.w = f2bf(ovb[dt][3] * rB);
    *(ushort4*)&o[orowA + dt * 16 + g * 4] = wa;
    *(ushort4*)&o[orowB + dt * 16 + g * 4] = wb;
  }
}

// ---------- launcher ----------
extern "C" void kernel_launch(void* const* d_in, const int* in_sizes, int n_in,
                              void* d_out, int out_size, void* d_ws, size_t ws_size,
                              hipStream_t stream) {
  const float* x      = (const float*)d_in[0];
  const float* sin_t  = (const float*)d_in[1];
  const float* cos_t  = (const float*)d_in[2];
  const float* w_qkv  = (const float*)d_in[3];
  const float* w_proj = (const float*)d_in[4];
  const float* b_proj = (const float*)d_in[5];
  float* out = (float*)d_out;

  char* ws = (char*)d_ws;
  unsigned short* xb     = (unsigned short*)(ws);                 // 16 MiB
  unsigned short* wqkvb  = (unsigned short*)(ws + (16l << 20));   // 6 MiB
  unsigned short* wprojb = (unsigned short*)(ws + (22l << 20));   // 2 MiB
  unsigned short* Qf     = (unsigned short*)(ws + (24l << 20));   // 16 MiB
  unsigned short* Kf     = (unsigned short*)(ws + (40l << 20));   // 16 MiB
  unsigned short* Vb     = (unsigned short*)(ws + (56l << 20));   // 16 MiB
  unsigned short* Vt     = (unsigned short*)(ws + (72l << 20));   // 16 MiB
  unsigned short* ob     = xb;   // alias: xb dead after QKV GEMM

  k_cvt_all<<<12288, 256, 0, stream>>>(x, w_qkv, w_proj, xb, wqkvb, wprojb);

  k_gemm_qkv<<<dim3(24, 64), 256, 0, stream>>>(xb, wqkvb, Qf, Kf, Vb,
                                               sin_t, cos_t);
  k_vtrans<<<dim3(8, 64), 256, 0, stream>>>(Vb, Vt);
  k_flash<<<dim3(1024), 256, 0, stream>>>(Qf, Kf, Vt, ob);
  k_gemm_proj<<<dim3(8, 64), 256, 0, stream>>>(ob, wprojb, out, b_proj,
                                               8192, 1024, 1024);
}

// Round 15
// 242.094 us; speedup vs baseline: 1.5166x; 1.0702x over previous
//
#include <hip/hip_runtime.h>
#include <stdint.h>

// ---------- types ----------
typedef __bf16 bf16x8 __attribute__((ext_vector_type(8)));
typedef _Float16 f16x8 __attribute__((ext_vector_type(8)));
typedef float f32x4 __attribute__((ext_vector_type(4)));
typedef short s16x8 __attribute__((ext_vector_type(8)));
typedef short s16x4 __attribute__((ext_vector_type(4)));
typedef unsigned int u32x4 __attribute__((ext_vector_type(4)));

__device__ __forceinline__ unsigned short f2bf(float f) {
  unsigned u = __builtin_bit_cast(unsigned, f);
  u += 0x7fff + ((u >> 16) & 1);   // RNE
  return (unsigned short)(u >> 16);
}
__device__ __forceinline__ unsigned short f2h(float f) {
  return __builtin_bit_cast(unsigned short, (_Float16)f);
}
__device__ __forceinline__ float exp2i(float x) {    // v_exp_f32 = 2^x
  float r;
  asm("v_exp_f32 %0, %1" : "=v"(r) : "v"(x));
  return r;
}
__device__ __forceinline__ unsigned cvtpkh(float lo, float hi) {  // 2xf32 -> packed fp16
  auto r = __builtin_amdgcn_cvt_pkrtz(lo, hi);
  return __builtin_bit_cast(unsigned, r);
}

__device__ __forceinline__ void gload_lds16(const void* g, void* l) {
  __builtin_amdgcn_global_load_lds(
      (const __attribute__((address_space(1))) unsigned int*)g,
      (__attribute__((address_space(3))) unsigned int*)l, 16, 0, 0);
}

__device__ __forceinline__ f32x4 mfma_bf(bf16x8 a, bf16x8 b, f32x4 c) {
  return __builtin_amdgcn_mfma_f32_16x16x32_bf16(a, b, c, 0, 0, 0);
}
__device__ __forceinline__ f32x4 mfma_h(f16x8 a, f16x8 b, f32x4 c) {
  return __builtin_amdgcn_mfma_f32_16x16x32_f16(a, b, c, 0, 0, 0);
}
__device__ __forceinline__ bf16x8 bc8(s16x8 v) { return __builtin_bit_cast(bf16x8, v); }
__device__ __forceinline__ f16x8 hc8(s16x8 v) { return __builtin_bit_cast(f16x8, v); }

// ---------- fp32 -> bf16 convert (x, w_qkv, w_proj in one launch) ----------
__global__ void k_cvt_all(const float* __restrict__ x, const float* __restrict__ wq,
                          const float* __restrict__ wp,
                          unsigned short* __restrict__ xb,
                          unsigned short* __restrict__ wqb,
                          unsigned short* __restrict__ wpb) {
  int i = blockIdx.x * blockDim.x + threadIdx.x;
  const float* in; unsigned short* out; int j = i;
  if (i < 2097152)        { in = x;  out = xb;  }
  else if (i < 2883584)   { in = wq; out = wqb; j = i - 2097152; }
  else                    { in = wp; out = wpb; j = i - 2883584; }
  float4 v = ((const float4*)in)[j];
  ushort4 o;
  o.x = f2bf(v.x); o.y = f2bf(v.y); o.z = f2bf(v.z); o.w = f2bf(v.w);
  ((ushort4*)out)[j] = o;
}

// ---------- QKV GEMM with fused RoPE + fp16 pack epilogue ----------
// Q pre-scaled by 0.125*log2(e) in fp32 -> flash softmax runs in exp2 domain.
__global__ __launch_bounds__(256) void k_gemm_qkv(
    const unsigned short* __restrict__ A, const unsigned short* __restrict__ Bm,
    unsigned short* __restrict__ Qf, unsigned short* __restrict__ Kf,
    unsigned short* __restrict__ Vb,
    const float* __restrict__ sin_t, const float* __restrict__ cos_t) {
  const int M_K = 1024;
  __shared__ unsigned short As[128 * 32];
  __shared__ unsigned short Bs[128 * 32];
  const int tid = threadIdx.x;
  const int lane = tid & 63;
  const int l15 = lane & 15, g = lane >> 4;
  const int wid = tid >> 6, wr = wid >> 1, wc = wid & 1;
  const long m0 = (long)blockIdx.y * 128, n0 = (long)blockIdx.x * 128;

  f32x4 acc[4][4] = {};

  for (int k0 = 0; k0 < M_K; k0 += 32) {
#pragma unroll
    for (int p = 0; p < 2; ++p) {
      int e = p * 256 + tid;
      int row = e >> 2, col = (e & 3) * 8;
      gload_lds16(A + (m0 + row) * M_K + k0 + col, (char*)As + e * 16);
      gload_lds16(Bm + (n0 + row) * M_K + k0 + col, (char*)Bs + e * 16);
    }
    __syncthreads();
    bf16x8 af[4], bfr[4];
#pragma unroll
    for (int i = 0; i < 4; ++i) {
      af[i]  = bc8(*(const s16x8*)&As[(wr * 64 + i * 16 + l15) * 32 + g * 8]);
      bfr[i] = bc8(*(const s16x8*)&Bs[(wc * 64 + i * 16 + l15) * 32 + g * 8]);
    }
#pragma unroll
    for (int mi = 0; mi < 4; ++mi)
#pragma unroll
      for (int ni = 0; ni < 4; ++ni)
        acc[mi][ni] = mfma_bf(af[mi], bfr[ni], acc[mi][ni]);
    __syncthreads();
  }

  const int colbase = (int)n0 + wc * 64;
  const int s  = colbase >> 10;           // 0=q 1=k 2=v
  const int h  = (colbase >> 6) & 15;
  const float QSC = 0.125f * 1.44269504089f;
#pragma unroll
  for (int mi = 0; mi < 4; ++mi)
#pragma unroll
    for (int r = 0; r < 4; ++r) {
      long m = m0 + wr * 64 + mi * 16 + g * 4 + r;
      int b = (int)(m >> 11), n = (int)(m & 2047);
      long slab = ((long)(b * 16 + h)) * 131072 + (long)n * 64;
      float v0 = acc[mi][0][r], v1 = acc[mi][1][r];
      float v2 = acc[mi][2][r], v3 = acc[mi][3][r];
      if (s == 2) {
        Vb[slab + l15]      = f2h(v0);
        Vb[slab + 16 + l15] = f2h(v1);
        Vb[slab + 32 + l15] = f2h(v2);
        Vb[slab + 48 + l15] = f2h(v3);
      } else {
        float o0 = v0, o1 = v1, o2 = v2, o3 = v3;
        if (n >= 4) {
          const float* cs = cos_t + (long)(n - 4) * 64;
          const float* sn = sin_t + (long)(n - 4) * 64;
          float c0 = cs[l15], c1 = cs[16 + l15], c2 = cs[32 + l15], c3 = cs[48 + l15];
          float s0 = sn[l15], s1 = sn[16 + l15], s2 = sn[32 + l15], s3 = sn[48 + l15];
          float t0 = o0, t1 = o1;
          o0 = o0 * c0 - o2 * s0;  o1 = o1 * c1 - o3 * s1;
          o2 = o2 * c2 + t0 * s2;  o3 = o3 * c3 + t1 * s3;
        }
        if (s == 0) { o0 *= QSC; o1 *= QSC; o2 *= QSC; o3 *= QSC; }
        unsigned short* H = (s == 0) ? Qf : Kf;
        H[slab + l15]      = f2h(o0);
        H[slab + 16 + l15] = f2h(o1);
        H[slab + 32 + l15] = f2h(o2);
        H[slab + 48 + l15] = f2h(o3);
      }
    }
}

// ---------- V transpose + key-permute ----------
// Vb [bh][2048 n][64 d] -> Vt [bh][64 d][2048 p]; within each 64-key tile,
// key kappa = 16*kt + 4*gg + r -> position p = ((kt&1)*4+gg)*8 + (kt>>1)*4 + r,
// so flash's PV B-operand comes straight from its pb registers.
__global__ __launch_bounds__(256) void k_vtrans(const unsigned short* __restrict__ Vb,
                                                unsigned short* __restrict__ Vt) {
  __shared__ unsigned short T[64 * 256];
  const int tid = threadIdx.x;
  const int bh = blockIdx.y;
  const int n0 = blockIdx.x * 256;
  const long slab = (long)bh * 131072;
#pragma unroll
  for (int it = 0; it < 8; ++it) {
    int u = it * 256 + tid;
    int key = u >> 3, dc = u & 7;
    s16x8 v = *(const s16x8*)&Vb[slab + (long)(n0 + key) * 64 + dc * 8];
#pragma unroll
    for (int i = 0; i < 8; ++i) {
      int d = dc * 8 + i;
      T[d * 256 + (key ^ (dc << 3))] = (unsigned short)v[i];
    }
  }
  __syncthreads();
#pragma unroll
  for (int it = 0; it < 8; ++it) {
    int w = it * 256 + tid;
    int d = w >> 5, uc = w & 31;           // uc: 16B-unit within 256-key row
    int tile = uc >> 3, unit = uc & 7;
    int hh = unit >> 2, gg = unit & 3;
    int ka = tile * 64 + hh * 16 + gg * 4; // keys ka..ka+3 and ka+32..ka+35
    int dc = d >> 3;
    s16x4 a = *(const s16x4*)&T[d * 256 + (ka ^ (dc << 3))];
    s16x4 b = *(const s16x4*)&T[d * 256 + ((ka + 32) ^ (dc << 3))];
    s16x8 v = {a[0], a[1], a[2], a[3], b[0], b[1], b[2], b[3]};
    *(s16x8*)&Vt[slab + (long)d * 2048 + n0 + uc * 8] = v;
  }
}

// ---------- generic bf16 GEMM (final projection), f32 out + bias ----------
__global__ __launch_bounds__(256) void k_gemm_proj(
    const unsigned short* __restrict__ A, const unsigned short* __restrict__ Bm,
    float* __restrict__ Cf, const float* __restrict__ bias, int M, int N, int K) {
  __shared__ unsigned short As[128 * 32];
  __shared__ unsigned short Bs[128 * 32];
  const int tid = threadIdx.x;
  const int lane = tid & 63;
  const int l15 = lane & 15, g = lane >> 4;
  const int wid = tid >> 6, wr = wid >> 1, wc = wid & 1;
  const long m0 = (long)blockIdx.y * 128, n0 = (long)blockIdx.x * 128;

  f32x4 acc[4][4] = {};

  for (int k0 = 0; k0 < K; k0 += 32) {
#pragma unroll
    for (int p = 0; p < 2; ++p) {
      int e = p * 256 + tid;
      int row = e >> 2, col = (e & 3) * 8;
      gload_lds16(A + (m0 + row) * K + k0 + col, (char*)As + e * 16);
      gload_lds16(Bm + (n0 + row) * K + k0 + col, (char*)Bs + e * 16);
    }
    __syncthreads();
    bf16x8 af[4], bfr[4];
#pragma unroll
    for (int i = 0; i < 4; ++i) {
      af[i]  = bc8(*(const s16x8*)&As[(wr * 64 + i * 16 + l15) * 32 + g * 8]);
      bfr[i] = bc8(*(const s16x8*)&Bs[(wc * 64 + i * 16 + l15) * 32 + g * 8]);
    }
#pragma unroll
    for (int mi = 0; mi < 4; ++mi)
#pragma unroll
      for (int ni = 0; ni < 4; ++ni)
        acc[mi][ni] = mfma_bf(af[mi], bfr[ni], acc[mi][ni]);
    __syncthreads();
  }

#pragma unroll
  for (int mi = 0; mi < 4; ++mi)
#pragma unroll
    for (int ni = 0; ni < 4; ++ni) {
      long col = n0 + wc * 64 + ni * 16 + l15;
#pragma unroll
      for (int r = 0; r < 4; ++r) {
        long row = m0 + wr * 64 + mi * 16 + g * 4 + r;
        Cf[row * N + col] = acc[mi][ni][r] + bias[col];
      }
    }
}

// ---------- MFMA flash attention (fp16, 32 q/wave, KVBLK=128, 16 rounds) ----------
// Two 64-key tiles per barrier round -> per-round fixed costs (barrier drain,
// cross-lane max shfl, defer check, loop/stage overhead) paid 16x not 32x.
// Same layouts/swizzles as r12/r14 (kt extended 0..7; PV indexes 64-key subtile).
// LDS: KS 2x16KB + VtS 2x16KB = 64 KiB. XCD-local bh swizzle (r14, FETCH -5.6x).
__global__ __launch_bounds__(256) void k_flash(
    const unsigned short* __restrict__ Qf, const unsigned short* __restrict__ Kf,
    const unsigned short* __restrict__ Vt, unsigned short* __restrict__ o) {
  __shared__ unsigned short KS[2][128 * 64];
  __shared__ unsigned short VtS[2][64 * 128];
  const int tid = threadIdx.x;
  const int lane = tid & 63, wid = tid >> 6;
  const int l15 = lane & 15, g = lane >> 4;
  const int j = blockIdx.x;
  const int c = j & 7, s = j >> 3;
  const int bh = ((s >> 4) << 3) | c;      // bijective: bh in [0,64)
  const int qt = s & 15;
  const int b = bh >> 4, h = bh & 15;
  const int q0 = qt * 128 + wid * 32;
  const long slab = (long)bh * 131072;

  const long qrowA = slab + (long)(q0 + l15) * 64;
  const long qrowB = slab + (long)(q0 + 16 + l15) * 64;
  f16x8 qa0 = hc8(*(const s16x8*)&Qf[qrowA + g * 8]);
  f16x8 qa1 = hc8(*(const s16x8*)&Qf[qrowA + 32 + g * 8]);
  f16x8 qb0 = hc8(*(const s16x8*)&Qf[qrowB + g * 8]);
  f16x8 qb1 = hc8(*(const s16x8*)&Qf[qrowB + 32 + g * 8]);

  f32x4 ova[4] = {}, ovb[4] = {};
  float mrunA = -1e30f, lrunA = 0.f;
  float mrunB = -1e30f, lrunB = 0.f;

  // staging: K 128x64 (1024 units), V^T 64x128 (1024 units); 4 loads each/thread.
  // Swizzle terms are p-invariant (p*32 / p*16 are multiples of 8).
  const int cK = (tid & 7) ^ ((tid >> 3) & 7);
  const int cV = (tid & 7) ^ ((tid >> 4) & 7);
  const int ktV = (tid >> 3) & 1;
  const unsigned short* kSrc = Kf + slab + (long)(tid >> 3) * 64 + cK * 8;
  const unsigned short* vSrc = Vt + slab + (long)(tid >> 4) * 2048 + ktV * 64 + cV * 8;

  auto stage = [&](int buf) {
#pragma unroll
    for (int p = 0; p < 4; ++p) {
      gload_lds16(kSrc + p * 2048,  (char*)&KS[buf][0]  + (p * 256 + tid) * 16);
      gload_lds16(vSrc + p * 32768, (char*)&VtS[buf][0] + (p * 256 + tid) * 16);
    }
    kSrc += 8192;   // next 128-key group: 128 rows x 64
    vSrc += 128;    // next 128 keys along the 2048-key rows
  };

  stage(0);
  __syncthreads();                  // round 0 fully resident (all waves)

  for (int t = 0; t < 16; ++t) {
    const int cur = t & 1;
    if (t < 15) stage(cur ^ 1);     // prefetch; drains at end-of-round barrier

    // QK^T over 128 keys: kt = 0..7, each K fragment feeds BOTH query groups
    f32x4 sa[8], sb[8];
    __builtin_amdgcn_s_setprio(1);
#pragma unroll
    for (int kt = 0; kt < 8; ++kt) {
      f32x4 xa = {}, xb = {};
#pragma unroll
      for (int kk = 0; kk < 2; ++kk) {
        int row = kt * 16 + l15;
        int uu = row * 8 + ((kk * 4 + g) ^ (row & 7));
        f16x8 kf = hc8(*(const s16x8*)&KS[cur][uu * 8]);
        xa = mfma_h(kf, kk ? qa1 : qa0, xa);
        xb = mfma_h(kf, kk ? qb1 : qb0, xb);
      }
      sa[kt] = xa; sb[kt] = xb;
    }
    __builtin_amdgcn_s_setprio(0);

    // per-query round max (128 keys -> one cross-lane reduce pair per group)
    float ta = -1e30f, tb = -1e30f;
#pragma unroll
    for (int kt = 0; kt < 8; ++kt) {
      ta = fmaxf(ta, fmaxf(fmaxf(sa[kt][0], sa[kt][1]), fmaxf(sa[kt][2], sa[kt][3])));
      tb = fmaxf(tb, fmaxf(fmaxf(sb[kt][0], sb[kt][1]), fmaxf(sb[kt][2], sb[kt][3])));
    }
    ta = fmaxf(ta, __shfl_xor(ta, 16)); ta = fmaxf(ta, __shfl_xor(ta, 32));
    tb = fmaxf(tb, __shfl_xor(tb, 16)); tb = fmaxf(tb, __shfl_xor(tb, 32));

    // defer-max (THR=8 in log2 units; P bounded by 2^8, fp16-safe)
    if (!__all(ta <= mrunA + 8.f && tb <= mrunB + 8.f)) {
      float mA = fmaxf(mrunA, ta), mB = fmaxf(mrunB, tb);
      float cA = exp2i(mrunA - mA), cB = exp2i(mrunB - mB);
      lrunA *= cA; lrunB *= cB;
#pragma unroll
      for (int dt = 0; dt < 4; ++dt) { ova[dt] *= cA; ovb[dt] *= cB; }
      mrunA = mA; mrunB = mB;
    }

    unsigned pa[8][2], pbv[8][2];
#pragma unroll
    for (int kt = 0; kt < 8; ++kt) {
      float a0 = exp2i(sa[kt][0] - mrunA), a1 = exp2i(sa[kt][1] - mrunA);
      float a2 = exp2i(sa[kt][2] - mrunA), a3 = exp2i(sa[kt][3] - mrunA);
      float b0 = exp2i(sb[kt][0] - mrunB), b1 = exp2i(sb[kt][1] - mrunB);
      float b2 = exp2i(sb[kt][2] - mrunB), b3 = exp2i(sb[kt][3] - mrunB);
      lrunA += (a0 + a1) + (a2 + a3);
      lrunB += (b0 + b1) + (b2 + b3);
      pa[kt][0]  = cvtpkh(a0, a1); pa[kt][1]  = cvtpkh(a2, a3);
      pbv[kt][0] = cvtpkh(b0, b1); pbv[kt][1] = cvtpkh(b2, b3);
    }

    // PV over the two 64-key subtiles; each V fragment feeds BOTH query groups
    __builtin_amdgcn_s_setprio(1);
#pragma unroll
    for (int ktile = 0; ktile < 2; ++ktile) {
      int kb = ktile * 4;
#pragma unroll
      for (int h2 = 0; h2 < 2; ++h2) {
        u32x4 brawA = {pa[kb + h2][0], pa[kb + h2][1],
                       pa[kb + h2 + 2][0], pa[kb + h2 + 2][1]};
        u32x4 brawB = {pbv[kb + h2][0], pbv[kb + h2][1],
                       pbv[kb + h2 + 2][0], pbv[kb + h2 + 2][1]};
        f16x8 pfA = __builtin_bit_cast(f16x8, brawA);
        f16x8 pfB = __builtin_bit_cast(f16x8, brawB);
#pragma unroll
        for (int dt = 0; dt < 4; ++dt) {
          int d = dt * 16 + l15;
          int vv = d * 16 + ktile * 8 + ((h2 * 4 + g) ^ (d & 7));
          f16x8 vf = hc8(*(const s16x8*)&VtS[cur][vv * 8]);
          ova[dt] = mfma_h(vf, pfA, ova[dt]);
          ovb[dt] = mfma_h(vf, pfB, ovb[dt]);
        }
      }
    }
    __builtin_amdgcn_s_setprio(0);
    __syncthreads();   // drains this wave's prefetch + barriers all waves
  }

  lrunA += __shfl_xor(lrunA, 16); lrunA += __shfl_xor(lrunA, 32);
  lrunB += __shfl_xor(lrunB, 16); lrunB += __shfl_xor(lrunB, 32);
  float rA = 1.0f / lrunA, rB = 1.0f / lrunB;
  long orowA = ((long)(b * 2048 + q0 + l15)) * 1024 + h * 64;
  long orowB = ((long)(b * 2048 + q0 + 16 + l15)) * 1024 + h * 64;
#pragma unroll
  for (int dt = 0; dt < 4; ++dt) {
    ushort4 wa, wb;
    wa.x = f2bf(ova[dt][0] * rA); wa.y = f2bf(ova[dt][1] * rA);
    wa.z = f2bf(ova[dt][2] * rA); wa.w = f2bf(ova[dt][3] * rA);
    wb.x = f2bf(ovb[dt][0] * rB); wb.y = f2bf(ovb[dt][1] * rB);
    wb.z = f2bf(ovb[dt][2] * rB); wb.w = f2bf(ovb[dt][3] * rB);
    *(ushort4*)&o[orowA + dt * 16 + g * 4] = wa;
    *(ushort4*)&o[orowB + dt * 16 + g * 4] = wb;
  }
}

// ---------- launcher ----------
extern "C" void kernel_launch(void* const* d_in, const int* in_sizes, int n_in,
                              void* d_out, int out_size, void* d_ws, size_t ws_size,
                              hipStream_t stream) {
  const float* x      = (const float*)d_in[0];
  const float* sin_t  = (const float*)d_in[1];
  const float* cos_t  = (const float*)d_in[2];
  const float* w_qkv  = (const float*)d_in[3];
  const float* w_proj = (const float*)d_in[4];
  const float* b_proj = (const float*)d_in[5];
  float* out = (float*)d_out;

  char* ws = (char*)d_ws;
  unsigned short* xb     = (unsigned short*)(ws);                 // 16 MiB
  unsigned short* wqkvb  = (unsigned short*)(ws + (16l << 20));   // 6 MiB
  unsigned short* wprojb = (unsigned short*)(ws + (22l << 20));   // 2 MiB
  unsigned short* Qf     = (unsigned short*)(ws + (24l << 20));   // 16 MiB
  unsigned short* Kf     = (unsigned short*)(ws + (40l << 20));   // 16 MiB
  unsigned short* Vb     = (unsigned short*)(ws + (56l << 20));   // 16 MiB
  unsigned short* Vt     = (unsigned short*)(ws + (72l << 20));   // 16 MiB
  unsigned short* ob     = xb;   // alias: xb dead after QKV GEMM

  k_cvt_all<<<12288, 256, 0, stream>>>(x, w_qkv, w_proj, xb, wqkvb, wprojb);

  k_gemm_qkv<<<dim3(24, 64), 256, 0, stream>>>(xb, wqkvb, Qf, Kf, Vb,
                                               sin_t, cos_t);
  k_vtrans<<<dim3(8, 64), 256, 0, stream>>>(Vb, Vt);
  k_flash<<<dim3(1024), 256, 0, stream>>>(Qf, Kf, Vt, ob);
  k_gemm_proj<<<dim3(8, 64), 256, 0, stream>>>(ob, wprojb, out, b_proj,
                                               8192, 1024, 1024);
}